// Round 1
// baseline (955.184 us; speedup 1.0000x reference)
//
#include <hip/hip_runtime.h>
#include <hip/hip_bf16.h>
#include <math.h>

// Problem constants (fixed by setup_inputs)
constexpr int B = 256, P = 200, N = 200, E = 128, H = 8, D = 16;
constexpr float INV_SQRT_D = 0.25f;              // 1/sqrt(16)
constexpr float INV_SQRT_E = 0.08838834764831845f; // 1/sqrt(128)
constexpr float LOGIT_CLIP = 10.0f;
constexpr float INV_TEMP = 1.25f;                // 1/0.8
constexpr int TOP_K = 20;
constexpr int MAX_DELTA = 4;

__device__ __forceinline__ float dot4(float4 a, float4 b) {
    return a.x*b.x + a.y*b.y + a.z*b.z + a.w*b.w;
}

// ---------------------------------------------------------------------------
// GEMM: out[M,128] = X1[M,128] @ W1[128,128] (+ X2 @ W2) (+ bias)
// tile 64 rows x 128 cols per 256-thread block, thread tile 8x4
// ---------------------------------------------------------------------------
__global__ __launch_bounds__(256) void proj_kernel(
    const float* __restrict__ X1, const float* __restrict__ W1,
    const float* __restrict__ X2, const float* __restrict__ W2,
    const float* __restrict__ bias, float* __restrict__ out)
{
    __shared__ float4 xs[64][32];      // 64 rows x 128 floats
    const int tid = threadIdx.x;
    const int eg = tid & 31;           // column group: e = eg*4..eg*4+3
    const int rg = tid >> 5;           // 0..7
    const int r0 = rg * 8;             // rows r0..r0+7
    const long base = (long)blockIdx.x * 64;

    float acc[8][4];
    #pragma unroll
    for (int i = 0; i < 8; ++i)
        #pragma unroll
        for (int j = 0; j < 4; ++j) acc[i][j] = 0.f;

    for (int pass = 0; pass < 2; ++pass) {
        const float* X = pass ? X2 : X1;
        const float* W = pass ? W2 : W1;
        if (!X) break;
        if (pass) __syncthreads();
        const float4* X4 = (const float4*)X;
        for (int idx = tid; idx < 64 * 32; idx += 256) {
            int r = idx >> 5, c = idx & 31;
            xs[r][c] = X4[(base + r) * 32 + c];
        }
        __syncthreads();
        for (int c4 = 0; c4 < 32; ++c4) {
            float4 w0 = *(const float4*)&W[(c4*4+0)*128 + eg*4];
            float4 w1 = *(const float4*)&W[(c4*4+1)*128 + eg*4];
            float4 w2 = *(const float4*)&W[(c4*4+2)*128 + eg*4];
            float4 w3 = *(const float4*)&W[(c4*4+3)*128 + eg*4];
            #pragma unroll
            for (int i = 0; i < 8; ++i) {
                float4 xv = xs[r0 + i][c4];
                acc[i][0] += xv.x*w0.x + xv.y*w1.x + xv.z*w2.x + xv.w*w3.x;
                acc[i][1] += xv.x*w0.y + xv.y*w1.y + xv.z*w2.y + xv.w*w3.y;
                acc[i][2] += xv.x*w0.z + xv.y*w1.z + xv.z*w2.z + xv.w*w3.z;
                acc[i][3] += xv.x*w0.w + xv.y*w1.w + xv.z*w2.w + xv.w*w3.w;
            }
        }
    }

    float4 bv = make_float4(0.f, 0.f, 0.f, 0.f);
    if (bias) bv = *(const float4*)&bias[eg*4];
    float4* out4 = (float4*)out;
    #pragma unroll
    for (int i = 0; i < 8; ++i) {
        out4[(base + r0 + i) * 32 + eg] =
            make_float4(acc[i][0]+bv.x, acc[i][1]+bv.y, acc[i][2]+bv.z, acc[i][3]+bv.w);
    }
}

// ---------------------------------------------------------------------------
// Attention: one block per (b,h). k,v head-slices staged in LDS.
// Thread p computes its row: pass1 online (max,sumexp), pass2 recompute + PV.
// ---------------------------------------------------------------------------
__global__ __launch_bounds__(256) void attn_kernel(
    const float* __restrict__ q, const float* __restrict__ k,
    const float* __restrict__ v, const float* __restrict__ mask,
    float* __restrict__ out)
{
    __shared__ float4 ks[N][4];
    __shared__ float4 vs[N][4];
    const int b = blockIdx.x >> 3, h = blockIdx.x & 7;
    const int tid = threadIdx.x;
    const float4* k4 = (const float4*)k;
    const float4* v4 = (const float4*)v;
    for (int idx = tid; idx < N * 4; idx += 256) {
        int n = idx >> 2, c = idx & 3;
        size_t off = (size_t)(b * N + n) * 32 + h * 4 + c;
        ks[n][c & 3] = k4[off];
        vs[n][c & 3] = v4[off];
    }
    __syncthreads();

    const int p = tid;
    if (p >= P) return;

    const float4* qr = (const float4*)q + (size_t)(b * P + p) * 32 + h * 4;
    float4 q0 = qr[0], q1 = qr[1], q2 = qr[2], q3 = qr[3];
    const float4* m4 = (const float4*)mask + (size_t)(b * P + p) * (N / 4);

    float m = -INFINITY, l = 0.f;
    for (int n4 = 0; n4 < N / 4; ++n4) {
        float4 mv = m4[n4];
        float mvs[4] = {mv.x, mv.y, mv.z, mv.w};
        #pragma unroll
        for (int j = 0; j < 4; ++j) {
            int n = n4 * 4 + j;
            float s = dot4(q0, ks[n][0]) + dot4(q1, ks[n][1]) +
                      dot4(q2, ks[n][2]) + dot4(q3, ks[n][3]);
            s = s * INV_SQRT_D + mvs[j];
            float nm = fmaxf(m, s);
            l = l * __expf(m - nm) + __expf(s - nm);
            m = nm;
        }
    }
    float inv_l = 1.f / l;

    float o[16];
    #pragma unroll
    for (int d = 0; d < 16; ++d) o[d] = 0.f;
    for (int n4 = 0; n4 < N / 4; ++n4) {
        float4 mv = m4[n4];
        float mvs[4] = {mv.x, mv.y, mv.z, mv.w};
        #pragma unroll
        for (int j = 0; j < 4; ++j) {
            int n = n4 * 4 + j;
            float s = dot4(q0, ks[n][0]) + dot4(q1, ks[n][1]) +
                      dot4(q2, ks[n][2]) + dot4(q3, ks[n][3]);
            s = s * INV_SQRT_D + mvs[j];
            float w = __expf(s - m);
            float4 v0 = vs[n][0], v1 = vs[n][1], v2 = vs[n][2], v3 = vs[n][3];
            o[0]  += w*v0.x; o[1]  += w*v0.y; o[2]  += w*v0.z; o[3]  += w*v0.w;
            o[4]  += w*v1.x; o[5]  += w*v1.y; o[6]  += w*v1.z; o[7]  += w*v1.w;
            o[8]  += w*v2.x; o[9]  += w*v2.y; o[10] += w*v2.z; o[11] += w*v2.w;
            o[12] += w*v3.x; o[13] += w*v3.y; o[14] += w*v3.z; o[15] += w*v3.w;
        }
    }
    float4* out4 = (float4*)out;
    size_t ob = (size_t)(b * P + p) * 32 + h * 4;
    #pragma unroll
    for (int c = 0; c < 4; ++c)
        out4[ob + c] = make_float4(o[c*4]*inv_l, o[c*4+1]*inv_l,
                                   o[c*4+2]*inv_l, o[c*4+3]*inv_l);
}

// ---------------------------------------------------------------------------
// Pointer scores + logits: sc = mh[b] @ nodes[b]^T, fused tanh/bias/mask.
// 64x64 tile per block, thread tile 4x4 (interleaved, stride 16).
// ---------------------------------------------------------------------------
__global__ __launch_bounds__(256) void pointer_kernel(
    const float* __restrict__ mh, const float* __restrict__ nodes,
    const float* __restrict__ mask, const int* __restrict__ gid,
    const int* __restrict__ cmp, const float* __restrict__ btab,
    float* __restrict__ out)
{
    __shared__ float4 ns[64][33];     // nodes tile, padded (132 floats/row)
    const int b = blockIdx.z;
    const int p_base = blockIdx.y * 64;
    const int n_base = blockIdx.x * 64;
    const int tid = threadIdx.x;
    const int pi = tid >> 4;          // 0..15
    const int ni = tid & 15;          // 0..15

    const float4* nodes4 = (const float4*)nodes;
    for (int idx = tid; idx < 64 * 32; idx += 256) {
        int r = idx >> 5, c = idx & 31;
        float4 val = make_float4(0.f, 0.f, 0.f, 0.f);
        if (n_base + r < N) val = nodes4[(size_t)(b * N + n_base + r) * 32 + c];
        ns[r][c] = val;
    }
    __syncthreads();

    float acc[4][4];
    #pragma unroll
    for (int i = 0; i < 4; ++i)
        #pragma unroll
        for (int j = 0; j < 4; ++j) acc[i][j] = 0.f;

    const float4* mh4 = (const float4*)mh;
    for (int c4 = 0; c4 < 32; ++c4) {
        float4 a[4];
        #pragma unroll
        for (int i = 0; i < 4; ++i) {
            int p = p_base + pi + 16 * i;
            int pr = p < P ? p : P - 1;
            a[i] = mh4[(size_t)(b * P + pr) * 32 + c4];
        }
        #pragma unroll
        for (int j = 0; j < 4; ++j) {
            float4 w = ns[ni + 16 * j][c4];
            #pragma unroll
            for (int i = 0; i < 4; ++i)
                acc[i][j] += dot4(a[i], w);
        }
    }

    float bt[MAX_DELTA + 1];
    #pragma unroll
    for (int t = 0; t <= MAX_DELTA; ++t) bt[t] = btab[t];

    #pragma unroll
    for (int i = 0; i < 4; ++i) {
        int p = p_base + pi + 16 * i;
        if (p >= P) continue;
        int cm = cmp[b * P + p];
        #pragma unroll
        for (int j = 0; j < 4; ++j) {
            int n = n_base + ni + 16 * j;
            if (n >= N) continue;
            int g = gid[b * N + n];
            int delta = g - cm;
            delta = delta < 0 ? 0 : (delta > MAX_DELTA ? MAX_DELTA : delta);
            float mv = mask[(size_t)(b * P + p) * N + n];
            float pb = isfinite(mv) ? bt[delta] : 0.f;
            float logit = LOGIT_CLIP * tanhf(acc[i][j] * INV_SQRT_E) + pb + mv;
            out[(size_t)(b * P + p) * N + n] = logit;
        }
    }
}

// ---------------------------------------------------------------------------
// Top-k (k=20) + temperature + renormalize, in place on d_out.
// One wave per row; 20x extract-max with (value, lowest-index) tie-break.
// ---------------------------------------------------------------------------
__global__ __launch_bounds__(256) void topk_kernel(float* __restrict__ io)
{
    const int wv = threadIdx.x >> 6, lane = threadIdx.x & 63;
    const long row = (long)blockIdx.x * 4 + wv;
    float* r = io + row * N;

    float l[4];
    bool valid[4], sel[4];
    #pragma unroll
    for (int j = 0; j < 4; ++j) {
        int n = lane + 64 * j;
        valid[j] = n < N;
        sel[j] = false;
        l[j] = valid[j] ? r[n] : -INFINITY;
    }

    float m0 = 0.f;
    for (int it = 0; it < TOP_K; ++it) {
        float bvv = -INFINITY;
        int bi = 1 << 30;
        #pragma unroll
        for (int j = 0; j < 4; ++j) {
            if (valid[j] && !sel[j]) {
                int idx = lane + 64 * j;
                if (l[j] > bvv || (l[j] == bvv && idx < bi)) { bvv = l[j]; bi = idx; }
            }
        }
        #pragma unroll
        for (int off = 32; off > 0; off >>= 1) {
            float ov = __shfl_xor(bvv, off);
            int oi = __shfl_xor(bi, off);
            if (ov > bvv || (ov == bvv && oi < bi)) { bvv = ov; bi = oi; }
        }
        if (it == 0) m0 = bvv;
        int dd = bi - lane;
        if (dd >= 0 && dd < 256 && (dd & 63) == 0) sel[dd >> 6] = true;
    }

    float e[4];
    float sum = 0.f;
    #pragma unroll
    for (int j = 0; j < 4; ++j) {
        e[j] = sel[j] ? __expf((l[j] - m0) * INV_TEMP) : 0.f;
        sum += e[j];
    }
    #pragma unroll
    for (int off = 32; off > 0; off >>= 1) sum += __shfl_xor(sum, off);
    float inv = 1.f / sum;
    #pragma unroll
    for (int j = 0; j < 4; ++j)
        if (valid[j]) r[lane + 64 * j] = e[j] * inv;
}

// ---------------------------------------------------------------------------
extern "C" void kernel_launch(void* const* d_in, const int* in_sizes, int n_in,
                              void* d_out, int out_size, void* d_ws, size_t ws_size,
                              hipStream_t stream) {
    const float* nodes = (const float*)d_in[0];
    const float* first = (const float*)d_in[1];
    const float* last  = (const float*)d_in[2];
    const float* mask  = (const float*)d_in[3];
    const int*   gid   = (const int*)d_in[4];
    const int*   cmp   = (const int*)d_in[5];
    const float* Wqf   = (const float*)d_in[6];
    const float* Wql   = (const float*)d_in[7];
    const float* Wk    = (const float*)d_in[8];
    const float* Wv    = (const float*)d_in[9];
    const float* Wc    = (const float*)d_in[10];
    const float* bc    = (const float*)d_in[11];
    const float* btab  = (const float*)d_in[12];
    float* out = (float*)d_out;

    float* ws   = (float*)d_ws;
    const size_t SLOT = (size_t)B * P * E;   // 6,553,600 floats
    float* qb  = ws;                 // q, later reused for mh
    float* kb  = ws + SLOT;
    float* vb  = ws + 2 * SLOT;
    float* ao  = ws + 3 * SLOT;      // attention output (concat heads)

    const int M = B * P;             // 51200 rows (= B*N too)

    // q = first@Wqf + last@Wql ; k = nodes@Wk ; v = nodes@Wv
    proj_kernel<<<M / 64, 256, 0, stream>>>(first, Wqf, last, Wql, nullptr, qb);
    proj_kernel<<<M / 64, 256, 0, stream>>>(nodes, Wk, nullptr, nullptr, nullptr, kb);
    proj_kernel<<<M / 64, 256, 0, stream>>>(nodes, Wv, nullptr, nullptr, nullptr, vb);

    // masked MHA
    attn_kernel<<<B * H, 256, 0, stream>>>(qb, kb, vb, mask, ao);

    // mh = ao @ Wc + bc   (into q's slot — q is dead now)
    proj_kernel<<<M / 64, 256, 0, stream>>>(ao, Wc, nullptr, nullptr, bc, qb);

    // pointer logits into d_out
    dim3 pgrid((N + 63) / 64, (P + 63) / 64, B);
    pointer_kernel<<<pgrid, 256, 0, stream>>>(qb, nodes, mask, gid, cmp, btab, out);

    // top-k + renormalize in place
    topk_kernel<<<(B * P) / 4, 256, 0, stream>>>(out);
}

// Round 2
// 814.758 us; speedup vs baseline: 1.1724x; 1.1724x over previous
//
#include <hip/hip_runtime.h>
#include <hip/hip_bf16.h>
#include <math.h>

// Problem constants (fixed by setup_inputs)
constexpr int B = 256, P = 200, N = 200, E = 128, H = 8, D = 16;
constexpr float INV_SQRT_D = 0.25f;              // 1/sqrt(16)
constexpr float INV_SQRT_E = 0.08838834764831845f; // 1/sqrt(128)
constexpr float LOGIT_CLIP = 10.0f;
constexpr float INV_TEMP = 1.25f;                // 1/0.8
constexpr int TOP_K = 20;
constexpr int MAX_DELTA = 4;

__device__ __forceinline__ float dot4(float4 a, float4 b) {
    return a.x*b.x + a.y*b.y + a.z*b.z + a.w*b.w;
}

// ---------------------------------------------------------------------------
// GEMM: out[M,128] = X1[M,128] @ W1[128,128] (+ X2 @ W2) (+ bias)
// tile 64 rows x 128 cols per 256-thread block, thread tile 8x4
// ---------------------------------------------------------------------------
__global__ __launch_bounds__(256) void proj_kernel(
    const float* __restrict__ X1, const float* __restrict__ W1,
    const float* __restrict__ X2, const float* __restrict__ W2,
    const float* __restrict__ bias, float* __restrict__ out)
{
    __shared__ float4 xs[64][32];      // 64 rows x 128 floats
    const int tid = threadIdx.x;
    const int eg = tid & 31;           // column group: e = eg*4..eg*4+3
    const int rg = tid >> 5;           // 0..7
    const int r0 = rg * 8;             // rows r0..r0+7
    const long base = (long)blockIdx.x * 64;

    float acc[8][4];
    #pragma unroll
    for (int i = 0; i < 8; ++i)
        #pragma unroll
        for (int j = 0; j < 4; ++j) acc[i][j] = 0.f;

    for (int pass = 0; pass < 2; ++pass) {
        const float* X = pass ? X2 : X1;
        const float* W = pass ? W2 : W1;
        if (!X) break;
        if (pass) __syncthreads();
        const float4* X4 = (const float4*)X;
        for (int idx = tid; idx < 64 * 32; idx += 256) {
            int r = idx >> 5, c = idx & 31;
            xs[r][c] = X4[(base + r) * 32 + c];
        }
        __syncthreads();
        for (int c4 = 0; c4 < 32; ++c4) {
            float4 w0 = *(const float4*)&W[(c4*4+0)*128 + eg*4];
            float4 w1 = *(const float4*)&W[(c4*4+1)*128 + eg*4];
            float4 w2 = *(const float4*)&W[(c4*4+2)*128 + eg*4];
            float4 w3 = *(const float4*)&W[(c4*4+3)*128 + eg*4];
            #pragma unroll
            for (int i = 0; i < 8; ++i) {
                float4 xv = xs[r0 + i][c4];
                acc[i][0] += xv.x*w0.x + xv.y*w1.x + xv.z*w2.x + xv.w*w3.x;
                acc[i][1] += xv.x*w0.y + xv.y*w1.y + xv.z*w2.y + xv.w*w3.y;
                acc[i][2] += xv.x*w0.z + xv.y*w1.z + xv.z*w2.z + xv.w*w3.z;
                acc[i][3] += xv.x*w0.w + xv.y*w1.w + xv.z*w2.w + xv.w*w3.w;
            }
        }
    }

    float4 bv = make_float4(0.f, 0.f, 0.f, 0.f);
    if (bias) bv = *(const float4*)&bias[eg*4];
    float4* out4 = (float4*)out;
    #pragma unroll
    for (int i = 0; i < 8; ++i) {
        out4[(base + r0 + i) * 32 + eg] =
            make_float4(acc[i][0]+bv.x, acc[i][1]+bv.y, acc[i][2]+bv.z, acc[i][3]+bv.w);
    }
}

// ---------------------------------------------------------------------------
// Attention: single-pass flash. One block per (b,h), XCD-aware remap so the
// 8 h-blocks of each b run on the SAME XCD back-to-back (mask/k/v L2 reuse).
// k,v head-slices staged in LDS (broadcast reads). Scores tiled in registers.
// ---------------------------------------------------------------------------
template<int TN>
__device__ __forceinline__ void attn_tile(
    int t, const float4* __restrict__ m4,
    float4 q0, float4 q1, float4 q2, float4 q3,
    const float4 (*ks)[4], const float4 (*vs)[4],
    float& m, float& l, float* o)
{
    float mvf[TN];
    #pragma unroll
    for (int j4 = 0; j4 < TN / 4; ++j4) {
        float4 mv = m4[(t >> 2) + j4];
        mvf[j4*4+0] = mv.x; mvf[j4*4+1] = mv.y;
        mvf[j4*4+2] = mv.z; mvf[j4*4+3] = mv.w;
    }
    float s[TN];
    float tmax = -INFINITY;
    #pragma unroll
    for (int j = 0; j < TN; ++j) {
        int n = t + j;
        float sc = dot4(q0, ks[n][0]) + dot4(q1, ks[n][1]) +
                   dot4(q2, ks[n][2]) + dot4(q3, ks[n][3]);
        s[j] = sc * INV_SQRT_D + mvf[j];
        tmax = fmaxf(tmax, s[j]);
    }
    float nm = fmaxf(m, tmax);
    if (nm == -INFINITY) return;      // fully masked so far
    float scale = (m == -INFINITY) ? 0.f : __expf(m - nm);
    l *= scale;
    #pragma unroll
    for (int d = 0; d < 16; ++d) o[d] *= scale;
    #pragma unroll
    for (int j = 0; j < TN; ++j) {
        int n = t + j;
        float w = __expf(s[j] - nm);
        l += w;
        float4 v0 = vs[n][0], v1 = vs[n][1], v2 = vs[n][2], v3 = vs[n][3];
        o[0]  += w*v0.x; o[1]  += w*v0.y; o[2]  += w*v0.z; o[3]  += w*v0.w;
        o[4]  += w*v1.x; o[5]  += w*v1.y; o[6]  += w*v1.z; o[7]  += w*v1.w;
        o[8]  += w*v2.x; o[9]  += w*v2.y; o[10] += w*v2.z; o[11] += w*v2.w;
        o[12] += w*v3.x; o[13] += w*v3.y; o[14] += w*v3.z; o[15] += w*v3.w;
    }
    m = nm;
}

__global__ __launch_bounds__(256) void attn_kernel(
    const float* __restrict__ q, const float* __restrict__ k,
    const float* __restrict__ v, const float* __restrict__ mask,
    float* __restrict__ out)
{
    __shared__ float4 ks[N][4];
    __shared__ float4 vs[N][4];
    // XCD-aware remap: raw = g*64 + h*8 + bl, b = g*8 + bl.
    // raw % 8 == b % 8 for all h -> same-b blocks share one XCD's L2,
    // and the 8 h-blocks of a b are dispatched back-to-back.
    const int raw = blockIdx.x;
    const int g = raw >> 6, r = raw & 63;
    const int h = r >> 3;
    const int b = g * 8 + (r & 7);
    const int tid = threadIdx.x;
    const float4* k4 = (const float4*)k;
    const float4* v4 = (const float4*)v;
    for (int idx = tid; idx < N * 4; idx += 256) {
        int n = idx >> 2, c = idx & 3;
        size_t off = (size_t)(b * N + n) * 32 + h * 4 + c;
        ks[n][c] = k4[off];
        vs[n][c] = v4[off];
    }
    __syncthreads();

    const int p = tid;
    if (p >= P) return;

    const float4* qr = (const float4*)q + (size_t)(b * P + p) * 32 + h * 4;
    float4 q0 = qr[0], q1 = qr[1], q2 = qr[2], q3 = qr[3];
    const float4* m4 = (const float4*)(mask + (size_t)(b * P + p) * N);

    float m = -INFINITY, l = 0.f;
    float o[16];
    #pragma unroll
    for (int d = 0; d < 16; ++d) o[d] = 0.f;

    // N = 200 = 12*16 + 8
    for (int t = 0; t < 192; t += 16)
        attn_tile<16>(t, m4, q0, q1, q2, q3, ks, vs, m, l, o);
    attn_tile<8>(192, m4, q0, q1, q2, q3, ks, vs, m, l, o);

    float inv_l = 1.f / l;
    float4* out4 = (float4*)out;
    size_t ob = (size_t)(b * P + p) * 32 + h * 4;
    #pragma unroll
    for (int c = 0; c < 4; ++c)
        out4[ob + c] = make_float4(o[c*4]*inv_l, o[c*4+1]*inv_l,
                                   o[c*4+2]*inv_l, o[c*4+3]*inv_l);
}

// ---------------------------------------------------------------------------
// Pointer scores + logits: sc = mh[b] @ nodes[b]^T, fused tanh/bias/mask.
// 64x64 tile per block, thread tile 4x4 (interleaved, stride 16).
// ---------------------------------------------------------------------------
__global__ __launch_bounds__(256) void pointer_kernel(
    const float* __restrict__ mh, const float* __restrict__ nodes,
    const float* __restrict__ mask, const int* __restrict__ gid,
    const int* __restrict__ cmp, const float* __restrict__ btab,
    float* __restrict__ out)
{
    __shared__ float4 ns[64][33];     // nodes tile, padded (132 floats/row)
    const int b = blockIdx.z;
    const int p_base = blockIdx.y * 64;
    const int n_base = blockIdx.x * 64;
    const int tid = threadIdx.x;
    const int pi = tid >> 4;          // 0..15
    const int ni = tid & 15;          // 0..15

    const float4* nodes4 = (const float4*)nodes;
    for (int idx = tid; idx < 64 * 32; idx += 256) {
        int r = idx >> 5, c = idx & 31;
        float4 val = make_float4(0.f, 0.f, 0.f, 0.f);
        if (n_base + r < N) val = nodes4[(size_t)(b * N + n_base + r) * 32 + c];
        ns[r][c] = val;
    }
    __syncthreads();

    float acc[4][4];
    #pragma unroll
    for (int i = 0; i < 4; ++i)
        #pragma unroll
        for (int j = 0; j < 4; ++j) acc[i][j] = 0.f;

    const float4* mh4 = (const float4*)mh;
    for (int c4 = 0; c4 < 32; ++c4) {
        float4 a[4];
        #pragma unroll
        for (int i = 0; i < 4; ++i) {
            int p = p_base + pi + 16 * i;
            int pr = p < P ? p : P - 1;
            a[i] = mh4[(size_t)(b * P + pr) * 32 + c4];
        }
        #pragma unroll
        for (int j = 0; j < 4; ++j) {
            float4 w = ns[ni + 16 * j][c4];
            #pragma unroll
            for (int i = 0; i < 4; ++i)
                acc[i][j] += dot4(a[i], w);
        }
    }

    float bt[MAX_DELTA + 1];
    #pragma unroll
    for (int t = 0; t <= MAX_DELTA; ++t) bt[t] = btab[t];

    #pragma unroll
    for (int i = 0; i < 4; ++i) {
        int p = p_base + pi + 16 * i;
        if (p >= P) continue;
        int cm = cmp[b * P + p];
        #pragma unroll
        for (int j = 0; j < 4; ++j) {
            int n = n_base + ni + 16 * j;
            if (n >= N) continue;
            int g = gid[b * N + n];
            int delta = g - cm;
            delta = delta < 0 ? 0 : (delta > MAX_DELTA ? MAX_DELTA : delta);
            float mv = mask[(size_t)(b * P + p) * N + n];
            float pb = isfinite(mv) ? bt[delta] : 0.f;
            float logit = LOGIT_CLIP * tanhf(acc[i][j] * INV_SQRT_E) + pb + mv;
            out[(size_t)(b * P + p) * N + n] = logit;
        }
    }
}

// ---------------------------------------------------------------------------
// Top-k (k=20) + temperature + renormalize, in place on d_out.
// One wave per row; 20x extract-max with (value, lowest-index) tie-break.
// ---------------------------------------------------------------------------
__global__ __launch_bounds__(256) void topk_kernel(float* __restrict__ io)
{
    const int wv = threadIdx.x >> 6, lane = threadIdx.x & 63;
    const long row = (long)blockIdx.x * 4 + wv;
    float* r = io + row * N;

    float l[4];
    bool valid[4], sel[4];
    #pragma unroll
    for (int j = 0; j < 4; ++j) {
        int n = lane + 64 * j;
        valid[j] = n < N;
        sel[j] = false;
        l[j] = valid[j] ? r[n] : -INFINITY;
    }

    float m0 = 0.f;
    for (int it = 0; it < TOP_K; ++it) {
        float bvv = -INFINITY;
        int bi = 1 << 30;
        #pragma unroll
        for (int j = 0; j < 4; ++j) {
            if (valid[j] && !sel[j]) {
                int idx = lane + 64 * j;
                if (l[j] > bvv || (l[j] == bvv && idx < bi)) { bvv = l[j]; bi = idx; }
            }
        }
        #pragma unroll
        for (int off = 32; off > 0; off >>= 1) {
            float ov = __shfl_xor(bvv, off);
            int oi = __shfl_xor(bi, off);
            if (ov > bvv || (ov == bvv && oi < bi)) { bvv = ov; bi = oi; }
        }
        if (it == 0) m0 = bvv;
        int dd = bi - lane;
        if (dd >= 0 && dd < 256 && (dd & 63) == 0) sel[dd >> 6] = true;
    }

    float e[4];
    float sum = 0.f;
    #pragma unroll
    for (int j = 0; j < 4; ++j) {
        e[j] = sel[j] ? __expf((l[j] - m0) * INV_TEMP) : 0.f;
        sum += e[j];
    }
    #pragma unroll
    for (int off = 32; off > 0; off >>= 1) sum += __shfl_xor(sum, off);
    float inv = 1.f / sum;
    #pragma unroll
    for (int j = 0; j < 4; ++j)
        if (valid[j]) r[lane + 64 * j] = e[j] * inv;
}

// ---------------------------------------------------------------------------
extern "C" void kernel_launch(void* const* d_in, const int* in_sizes, int n_in,
                              void* d_out, int out_size, void* d_ws, size_t ws_size,
                              hipStream_t stream) {
    const float* nodes = (const float*)d_in[0];
    const float* first = (const float*)d_in[1];
    const float* last  = (const float*)d_in[2];
    const float* mask  = (const float*)d_in[3];
    const int*   gid   = (const int*)d_in[4];
    const int*   cmp   = (const int*)d_in[5];
    const float* Wqf   = (const float*)d_in[6];
    const float* Wql   = (const float*)d_in[7];
    const float* Wk    = (const float*)d_in[8];
    const float* Wv    = (const float*)d_in[9];
    const float* Wc    = (const float*)d_in[10];
    const float* bc    = (const float*)d_in[11];
    const float* btab  = (const float*)d_in[12];
    float* out = (float*)d_out;

    float* ws   = (float*)d_ws;
    const size_t SLOT = (size_t)B * P * E;   // 6,553,600 floats
    float* qb  = ws;                 // q, later reused for mh
    float* kb  = ws + SLOT;
    float* vb  = ws + 2 * SLOT;
    float* ao  = ws + 3 * SLOT;      // attention output (concat heads)

    const int M = B * P;             // 51200 rows (= B*N too)

    // q = first@Wqf + last@Wql ; k = nodes@Wk ; v = nodes@Wv
    proj_kernel<<<M / 64, 256, 0, stream>>>(first, Wqf, last, Wql, nullptr, qb);
    proj_kernel<<<M / 64, 256, 0, stream>>>(nodes, Wk, nullptr, nullptr, nullptr, kb);
    proj_kernel<<<M / 64, 256, 0, stream>>>(nodes, Wv, nullptr, nullptr, nullptr, vb);

    // masked MHA (single-pass flash, XCD-aware remap)
    attn_kernel<<<B * H, 256, 0, stream>>>(qb, kb, vb, mask, ao);

    // mh = ao @ Wc + bc   (into q's slot — q is dead now)
    proj_kernel<<<M / 64, 256, 0, stream>>>(ao, Wc, nullptr, nullptr, bc, qb);

    // pointer logits into d_out
    dim3 pgrid((N + 63) / 64, (P + 63) / 64, B);
    pointer_kernel<<<pgrid, 256, 0, stream>>>(qb, nodes, mask, gid, cmp, btab, out);

    // top-k + renormalize in place
    topk_kernel<<<(B * P) / 4, 256, 0, stream>>>(out);
}

// Round 4
// 678.742 us; speedup vs baseline: 1.4073x; 1.2004x over previous
//
#include <hip/hip_runtime.h>
#include <hip/hip_bf16.h>
#include <math.h>

// Problem constants (fixed by setup_inputs)
constexpr int B = 256, P = 200, N = 200, E = 128, H = 8, D = 16;
constexpr float INV_SQRT_D = 0.25f;              // 1/sqrt(16)
constexpr float INV_SQRT_E = 0.08838834764831845f; // 1/sqrt(128)
constexpr float LOGIT_CLIP = 10.0f;
constexpr float INV_TEMP = 1.25f;                // 1/0.8
constexpr int TOP_K = 20;
constexpr int MAX_DELTA = 4;

__device__ __forceinline__ float dot4(float4 a, float4 b) {
    return a.x*b.x + a.y*b.y + a.z*b.z + a.w*b.w;
}

// ---------------------------------------------------------------------------
// GEMM: out[M,128] = X1[M,128] @ W1[128,128] (+ X2 @ W2) (+ bias)
// tile 64 rows x 128 cols per 256-thread block, thread tile 8x4
// ---------------------------------------------------------------------------
__global__ __launch_bounds__(256) void proj_kernel(
    const float* __restrict__ X1, const float* __restrict__ W1,
    const float* __restrict__ X2, const float* __restrict__ W2,
    const float* __restrict__ bias, float* __restrict__ out)
{
    __shared__ float4 xs[64][32];      // 64 rows x 128 floats
    const int tid = threadIdx.x;
    const int eg = tid & 31;           // column group: e = eg*4..eg*4+3
    const int rg = tid >> 5;           // 0..7
    const int r0 = rg * 8;             // rows r0..r0+7
    const long base = (long)blockIdx.x * 64;

    float acc[8][4];
    #pragma unroll
    for (int i = 0; i < 8; ++i)
        #pragma unroll
        for (int j = 0; j < 4; ++j) acc[i][j] = 0.f;

    for (int pass = 0; pass < 2; ++pass) {
        const float* X = pass ? X2 : X1;
        const float* W = pass ? W2 : W1;
        if (!X) break;
        if (pass) __syncthreads();
        const float4* X4 = (const float4*)X;
        for (int idx = tid; idx < 64 * 32; idx += 256) {
            int r = idx >> 5, c = idx & 31;
            xs[r][c] = X4[(base + r) * 32 + c];
        }
        __syncthreads();
        for (int c4 = 0; c4 < 32; ++c4) {
            float4 w0 = *(const float4*)&W[(c4*4+0)*128 + eg*4];
            float4 w1 = *(const float4*)&W[(c4*4+1)*128 + eg*4];
            float4 w2 = *(const float4*)&W[(c4*4+2)*128 + eg*4];
            float4 w3 = *(const float4*)&W[(c4*4+3)*128 + eg*4];
            #pragma unroll
            for (int i = 0; i < 8; ++i) {
                float4 xv = xs[r0 + i][c4];
                acc[i][0] += xv.x*w0.x + xv.y*w1.x + xv.z*w2.x + xv.w*w3.x;
                acc[i][1] += xv.x*w0.y + xv.y*w1.y + xv.z*w2.y + xv.w*w3.y;
                acc[i][2] += xv.x*w0.z + xv.y*w1.z + xv.z*w2.z + xv.w*w3.z;
                acc[i][3] += xv.x*w0.w + xv.y*w1.w + xv.z*w2.w + xv.w*w3.w;
            }
        }
    }

    float4 bv = make_float4(0.f, 0.f, 0.f, 0.f);
    if (bias) bv = *(const float4*)&bias[eg*4];
    float4* out4 = (float4*)out;
    #pragma unroll
    for (int i = 0; i < 8; ++i) {
        out4[(base + r0 + i) * 32 + eg] =
            make_float4(acc[i][0]+bv.x, acc[i][1]+bv.y, acc[i][2]+bv.z, acc[i][3]+bv.w);
    }
}

// ---------------------------------------------------------------------------
// Attention: single-pass flash. One block per (b,h), XCD-aware remap so the
// 8 h-blocks of each b run on the SAME XCD back-to-back (mask/k/v L2 reuse).
// k,v head-slices staged in LDS (broadcast reads). Scores tiled in registers.
// ---------------------------------------------------------------------------
template<int TN>
__device__ __forceinline__ void attn_tile(
    int t, const float4* __restrict__ m4,
    float4 q0, float4 q1, float4 q2, float4 q3,
    const float4 (*ks)[4], const float4 (*vs)[4],
    float& m, float& l, float* o)
{
    float mvf[TN];
    #pragma unroll
    for (int j4 = 0; j4 < TN / 4; ++j4) {
        float4 mv = m4[(t >> 2) + j4];
        mvf[j4*4+0] = mv.x; mvf[j4*4+1] = mv.y;
        mvf[j4*4+2] = mv.z; mvf[j4*4+3] = mv.w;
    }
    float s[TN];
    float tmax = -INFINITY;
    #pragma unroll
    for (int j = 0; j < TN; ++j) {
        int n = t + j;
        float sc = dot4(q0, ks[n][0]) + dot4(q1, ks[n][1]) +
                   dot4(q2, ks[n][2]) + dot4(q3, ks[n][3]);
        s[j] = sc * INV_SQRT_D + mvf[j];
        tmax = fmaxf(tmax, s[j]);
    }
    float nm = fmaxf(m, tmax);
    if (nm == -INFINITY) return;      // fully masked so far
    float scale = (m == -INFINITY) ? 0.f : __expf(m - nm);
    l *= scale;
    #pragma unroll
    for (int d = 0; d < 16; ++d) o[d] *= scale;
    #pragma unroll
    for (int j = 0; j < TN; ++j) {
        int n = t + j;
        float w = __expf(s[j] - nm);
        l += w;
        float4 v0 = vs[n][0], v1 = vs[n][1], v2 = vs[n][2], v3 = vs[n][3];
        o[0]  += w*v0.x; o[1]  += w*v0.y; o[2]  += w*v0.z; o[3]  += w*v0.w;
        o[4]  += w*v1.x; o[5]  += w*v1.y; o[6]  += w*v1.z; o[7]  += w*v1.w;
        o[8]  += w*v2.x; o[9]  += w*v2.y; o[10] += w*v2.z; o[11] += w*v2.w;
        o[12] += w*v3.x; o[13] += w*v3.y; o[14] += w*v3.z; o[15] += w*v3.w;
    }
    m = nm;
}

__global__ __launch_bounds__(256) void attn_kernel(
    const float* __restrict__ q, const float* __restrict__ k,
    const float* __restrict__ v, const float* __restrict__ mask,
    float* __restrict__ out)
{
    __shared__ float4 ks[N][4];
    __shared__ float4 vs[N][4];
    // XCD-aware remap: raw = g*64 + h*8 + bl, b = g*8 + bl.
    // raw % 8 == b % 8 for all h -> same-b blocks share one XCD's L2,
    // and the 8 h-blocks of a b are dispatched back-to-back.
    const int raw = blockIdx.x;
    const int g = raw >> 6, r = raw & 63;
    const int h = r >> 3;
    const int b = g * 8 + (r & 7);
    const int tid = threadIdx.x;
    const float4* k4 = (const float4*)k;
    const float4* v4 = (const float4*)v;
    for (int idx = tid; idx < N * 4; idx += 256) {
        int n = idx >> 2, c = idx & 3;
        size_t off = (size_t)(b * N + n) * 32 + h * 4 + c;
        ks[n][c] = k4[off];
        vs[n][c] = v4[off];
    }
    __syncthreads();

    const int p = tid;
    if (p >= P) return;

    const float4* qr = (const float4*)q + (size_t)(b * P + p) * 32 + h * 4;
    float4 q0 = qr[0], q1 = qr[1], q2 = qr[2], q3 = qr[3];
    const float4* m4 = (const float4*)(mask + (size_t)(b * P + p) * N);

    float m = -INFINITY, l = 0.f;
    float o[16];
    #pragma unroll
    for (int d = 0; d < 16; ++d) o[d] = 0.f;

    // N = 200 = 12*16 + 8
    for (int t = 0; t < 192; t += 16)
        attn_tile<16>(t, m4, q0, q1, q2, q3, ks, vs, m, l, o);
    attn_tile<8>(192, m4, q0, q1, q2, q3, ks, vs, m, l, o);

    float inv_l = 1.f / l;
    float4* out4 = (float4*)out;
    size_t ob = (size_t)(b * P + p) * 32 + h * 4;
    #pragma unroll
    for (int c = 0; c < 4; ++c)
        out4[ob + c] = make_float4(o[c*4]*inv_l, o[c*4+1]*inv_l,
                                   o[c*4+2]*inv_l, o[c*4+3]*inv_l);
}

// ---------------------------------------------------------------------------
// Pointer scores + logits: sc = mh[b] @ nodes[b]^T, fused tanh/bias/mask.
// 64x64 tile per block, thread tile 4x4 (interleaved, stride 16).
// ---------------------------------------------------------------------------
__global__ __launch_bounds__(256) void pointer_kernel(
    const float* __restrict__ mh, const float* __restrict__ nodes,
    const float* __restrict__ mask, const int* __restrict__ gid,
    const int* __restrict__ cmp, const float* __restrict__ btab,
    float* __restrict__ out)
{
    __shared__ float4 ns[64][33];     // nodes tile, padded (132 floats/row)
    const int b = blockIdx.z;
    const int p_base = blockIdx.y * 64;
    const int n_base = blockIdx.x * 64;
    const int tid = threadIdx.x;
    const int pi = tid >> 4;          // 0..15
    const int ni = tid & 15;          // 0..15

    const float4* nodes4 = (const float4*)nodes;
    for (int idx = tid; idx < 64 * 32; idx += 256) {
        int r = idx >> 5, c = idx & 31;
        float4 val = make_float4(0.f, 0.f, 0.f, 0.f);
        if (n_base + r < N) val = nodes4[(size_t)(b * N + n_base + r) * 32 + c];
        ns[r][c] = val;
    }
    __syncthreads();

    float acc[4][4];
    #pragma unroll
    for (int i = 0; i < 4; ++i)
        #pragma unroll
        for (int j = 0; j < 4; ++j) acc[i][j] = 0.f;

    const float4* mh4 = (const float4*)mh;
    for (int c4 = 0; c4 < 32; ++c4) {
        float4 a[4];
        #pragma unroll
        for (int i = 0; i < 4; ++i) {
            int p = p_base + pi + 16 * i;
            int pr = p < P ? p : P - 1;
            a[i] = mh4[(size_t)(b * P + pr) * 32 + c4];
        }
        #pragma unroll
        for (int j = 0; j < 4; ++j) {
            float4 w = ns[ni + 16 * j][c4];
            #pragma unroll
            for (int i = 0; i < 4; ++i)
                acc[i][j] += dot4(a[i], w);
        }
    }

    float bt[MAX_DELTA + 1];
    #pragma unroll
    for (int t = 0; t <= MAX_DELTA; ++t) bt[t] = btab[t];

    #pragma unroll
    for (int i = 0; i < 4; ++i) {
        int p = p_base + pi + 16 * i;
        if (p >= P) continue;
        int cm = cmp[b * P + p];
        #pragma unroll
        for (int j = 0; j < 4; ++j) {
            int n = n_base + ni + 16 * j;
            if (n >= N) continue;
            int g = gid[b * N + n];
            int delta = g - cm;
            delta = delta < 0 ? 0 : (delta > MAX_DELTA ? MAX_DELTA : delta);
            float mv = mask[(size_t)(b * P + p) * N + n];
            float pb = isfinite(mv) ? bt[delta] : 0.f;
            float logit = LOGIT_CLIP * tanhf(acc[i][j] * INV_SQRT_E) + pb + mv;
            out[(size_t)(b * P + p) * N + n] = logit;
        }
    }
}

// ---------------------------------------------------------------------------
// Top-k (k=20) + temperature + renormalize, in place on d_out.
// One wave per row. Radix-select (32 ballot steps) finds the exact 20th
// largest value T; selection = {x > T} + {x == T, lowest index} (same
// tie-break as jax.lax.top_k). Softmax over selected relative to T.
// ---------------------------------------------------------------------------
__global__ __launch_bounds__(256) void topk_kernel(float* __restrict__ io)
{
    const int wv = threadIdx.x >> 6, lane = threadIdx.x & 63;
    const long row = (long)blockIdx.x * 4 + wv;
    float* r = io + row * N;

    float x[4];
    unsigned u[4];
    #pragma unroll
    for (int j = 0; j < 4; ++j) {
        int n = lane + 64 * j;
        bool valid = n < N;
        x[j] = valid ? r[n] : -INFINITY;
        unsigned bb = __float_as_uint(x[j]);
        // orderable mapping: larger float <-> larger uint; invalid -> 0 (min)
        u[j] = valid ? ((bb & 0x80000000u) ? ~bb : (bb | 0x80000000u)) : 0u;
    }

    // radix-select: after the loop, p == orderable(20th largest value)
    unsigned p = 0;
    for (int i = 31; i >= 0; --i) {
        unsigned c = p | (1u << i);
        int cnt = 0;
        #pragma unroll
        for (int j = 0; j < 4; ++j)
            cnt += (int)__popcll(__ballot(u[j] >= c));
        if (cnt >= TOP_K) p = c;
    }

    // elements strictly above threshold
    int cnt_gt = 0;
    #pragma unroll
    for (int j = 0; j < 4; ++j)
        cnt_gt += (int)__popcll(__ballot(u[j] > p));
    const int needed = TOP_K - cnt_gt;

    // select ties (u == p) in index order (n = lane + 64*j -> j-major)
    const unsigned long long lt_mask = (1ull << lane) - 1ull;
    bool sel[4];
    int eq_before = 0;
    #pragma unroll
    for (int j = 0; j < 4; ++j) {
        unsigned long long em = __ballot(u[j] == p);
        int myrank = eq_before + (int)__popcll(em & lt_mask);
        sel[j] = (u[j] > p) || ((u[j] == p) && (myrank < needed));
        eq_before += (int)__popcll(em);
    }

    // invert orderable mapping to get threshold as float
    unsigned tb = (p & 0x80000000u) ? (p & 0x7FFFFFFFu) : ~p;
    float Tf = __uint_as_float(tb);

    float e[4];
    float sum = 0.f;
    if (isfinite(Tf)) {
        #pragma unroll
        for (int j = 0; j < 4; ++j) {
            e[j] = sel[j] ? __expf((x[j] - Tf) * INV_TEMP) : 0.f;
            sum += e[j];
        }
    } else {
        // fully-masked row: selected entries are equal -> uniform weights
        #pragma unroll
        for (int j = 0; j < 4; ++j) {
            e[j] = sel[j] ? 1.f : 0.f;
            sum += e[j];
        }
    }
    #pragma unroll
    for (int off = 32; off > 0; off >>= 1) sum += __shfl_xor(sum, off);
    float inv = 1.f / sum;
    #pragma unroll
    for (int j = 0; j < 4; ++j) {
        int n = lane + 64 * j;
        if (n < N) r[n] = e[j] * inv;
    }
}

// ---------------------------------------------------------------------------
extern "C" void kernel_launch(void* const* d_in, const int* in_sizes, int n_in,
                              void* d_out, int out_size, void* d_ws, size_t ws_size,
                              hipStream_t stream) {
    const float* nodes = (const float*)d_in[0];
    const float* first = (const float*)d_in[1];
    const float* last  = (const float*)d_in[2];
    const float* mask  = (const float*)d_in[3];
    const int*   gid   = (const int*)d_in[4];
    const int*   cmp   = (const int*)d_in[5];
    const float* Wqf   = (const float*)d_in[6];
    const float* Wql   = (const float*)d_in[7];
    const float* Wk    = (const float*)d_in[8];
    const float* Wv    = (const float*)d_in[9];
    const float* Wc    = (const float*)d_in[10];
    const float* bc    = (const float*)d_in[11];
    const float* btab  = (const float*)d_in[12];
    float* out = (float*)d_out;

    float* ws   = (float*)d_ws;
    const size_t SLOT = (size_t)B * P * E;   // 6,553,600 floats
    float* qb  = ws;                 // q, later reused for mh
    float* kb  = ws + SLOT;
    float* vb  = ws + 2 * SLOT;
    float* ao  = ws + 3 * SLOT;      // attention output (concat heads)

    const int M = B * P;             // 51200 rows (= B*N too)

    // q = first@Wqf + last@Wql ; k = nodes@Wk ; v = nodes@Wv
    proj_kernel<<<M / 64, 256, 0, stream>>>(first, Wqf, last, Wql, nullptr, qb);
    proj_kernel<<<M / 64, 256, 0, stream>>>(nodes, Wk, nullptr, nullptr, nullptr, kb);
    proj_kernel<<<M / 64, 256, 0, stream>>>(nodes, Wv, nullptr, nullptr, nullptr, vb);

    // masked MHA (single-pass flash, XCD-aware remap)
    attn_kernel<<<B * H, 256, 0, stream>>>(qb, kb, vb, mask, ao);

    // mh = ao @ Wc + bc   (into q's slot — q is dead now)
    proj_kernel<<<M / 64, 256, 0, stream>>>(ao, Wc, nullptr, nullptr, bc, qb);

    // pointer logits into d_out
    dim3 pgrid((N + 63) / 64, (P + 63) / 64, B);
    pointer_kernel<<<pgrid, 256, 0, stream>>>(qb, nodes, mask, gid, cmp, btab, out);

    // top-k + renormalize in place
    topk_kernel<<<(B * P) / 4, 256, 0, stream>>>(out);
}

// Round 5
// 676.109 us; speedup vs baseline: 1.4128x; 1.0039x over previous
//
#include <hip/hip_runtime.h>
#include <hip/hip_bf16.h>
#include <math.h>

// Problem constants (fixed by setup_inputs)
constexpr int B = 256, P = 200, N = 200, E = 128, H = 8, D = 16;
constexpr float INV_SQRT_D = 0.25f;              // 1/sqrt(16)
constexpr float INV_SQRT_E = 0.08838834764831845f; // 1/sqrt(128)
constexpr float LOGIT_CLIP = 10.0f;
constexpr float INV_TEMP = 1.25f;                // 1/0.8
constexpr int TOP_K = 20;
constexpr int MAX_DELTA = 4;

__device__ __forceinline__ float dot4(float4 a, float4 b) {
    return a.x*b.x + a.y*b.y + a.z*b.z + a.w*b.w;
}

// ---------------------------------------------------------------------------
// GEMM: out[M,128] = X1[M,128] @ W1[128,128] (+ X2 @ W2) (+ bias)
// tile 64 rows x 128 cols per 256-thread block, thread tile 8x4
// ---------------------------------------------------------------------------
__global__ __launch_bounds__(256) void proj_kernel(
    const float* __restrict__ X1, const float* __restrict__ W1,
    const float* __restrict__ X2, const float* __restrict__ W2,
    const float* __restrict__ bias, float* __restrict__ out)
{
    __shared__ float4 xs[64][32];      // 64 rows x 128 floats
    const int tid = threadIdx.x;
    const int eg = tid & 31;           // column group: e = eg*4..eg*4+3
    const int rg = tid >> 5;           // 0..7
    const int r0 = rg * 8;             // rows r0..r0+7
    const long base = (long)blockIdx.x * 64;

    float acc[8][4];
    #pragma unroll
    for (int i = 0; i < 8; ++i)
        #pragma unroll
        for (int j = 0; j < 4; ++j) acc[i][j] = 0.f;

    for (int pass = 0; pass < 2; ++pass) {
        const float* X = pass ? X2 : X1;
        const float* W = pass ? W2 : W1;
        if (!X) break;
        if (pass) __syncthreads();
        const float4* X4 = (const float4*)X;
        for (int idx = tid; idx < 64 * 32; idx += 256) {
            int r = idx >> 5, c = idx & 31;
            xs[r][c] = X4[(base + r) * 32 + c];
        }
        __syncthreads();
        for (int c4 = 0; c4 < 32; ++c4) {
            float4 w0 = *(const float4*)&W[(c4*4+0)*128 + eg*4];
            float4 w1 = *(const float4*)&W[(c4*4+1)*128 + eg*4];
            float4 w2 = *(const float4*)&W[(c4*4+2)*128 + eg*4];
            float4 w3 = *(const float4*)&W[(c4*4+3)*128 + eg*4];
            #pragma unroll
            for (int i = 0; i < 8; ++i) {
                float4 xv = xs[r0 + i][c4];
                acc[i][0] += xv.x*w0.x + xv.y*w1.x + xv.z*w2.x + xv.w*w3.x;
                acc[i][1] += xv.x*w0.y + xv.y*w1.y + xv.z*w2.y + xv.w*w3.y;
                acc[i][2] += xv.x*w0.z + xv.y*w1.z + xv.z*w2.z + xv.w*w3.z;
                acc[i][3] += xv.x*w0.w + xv.y*w1.w + xv.z*w2.w + xv.w*w3.w;
            }
        }
    }

    float4 bv = make_float4(0.f, 0.f, 0.f, 0.f);
    if (bias) bv = *(const float4*)&bias[eg*4];
    float4* out4 = (float4*)out;
    #pragma unroll
    for (int i = 0; i < 8; ++i) {
        out4[(base + r0 + i) * 32 + eg] =
            make_float4(acc[i][0]+bv.x, acc[i][1]+bv.y, acc[i][2]+bv.z, acc[i][3]+bv.w);
    }
}

// ---------------------------------------------------------------------------
// Fused K+V projection: stage X tile once, compute X@Wk and X@Wv.
// ---------------------------------------------------------------------------
__global__ __launch_bounds__(256) void kv_proj_kernel(
    const float* __restrict__ X, const float* __restrict__ Wk,
    const float* __restrict__ Wv, float* __restrict__ outK,
    float* __restrict__ outV)
{
    __shared__ float4 xs[64][32];
    const int tid = threadIdx.x;
    const int eg = tid & 31;
    const int rg = tid >> 5;
    const int r0 = rg * 8;
    const long base = (long)blockIdx.x * 64;

    float acck[8][4], accv[8][4];
    #pragma unroll
    for (int i = 0; i < 8; ++i)
        #pragma unroll
        for (int j = 0; j < 4; ++j) { acck[i][j] = 0.f; accv[i][j] = 0.f; }

    const float4* X4 = (const float4*)X;
    for (int idx = tid; idx < 64 * 32; idx += 256) {
        int r = idx >> 5, c = idx & 31;
        xs[r][c] = X4[(base + r) * 32 + c];
    }
    __syncthreads();

    for (int c4 = 0; c4 < 32; ++c4) {
        float4 k0 = *(const float4*)&Wk[(c4*4+0)*128 + eg*4];
        float4 k1 = *(const float4*)&Wk[(c4*4+1)*128 + eg*4];
        float4 k2 = *(const float4*)&Wk[(c4*4+2)*128 + eg*4];
        float4 k3 = *(const float4*)&Wk[(c4*4+3)*128 + eg*4];
        float4 v0 = *(const float4*)&Wv[(c4*4+0)*128 + eg*4];
        float4 v1 = *(const float4*)&Wv[(c4*4+1)*128 + eg*4];
        float4 v2 = *(const float4*)&Wv[(c4*4+2)*128 + eg*4];
        float4 v3 = *(const float4*)&Wv[(c4*4+3)*128 + eg*4];
        #pragma unroll
        for (int i = 0; i < 8; ++i) {
            float4 xv = xs[r0 + i][c4];
            acck[i][0] += xv.x*k0.x + xv.y*k1.x + xv.z*k2.x + xv.w*k3.x;
            acck[i][1] += xv.x*k0.y + xv.y*k1.y + xv.z*k2.y + xv.w*k3.y;
            acck[i][2] += xv.x*k0.z + xv.y*k1.z + xv.z*k2.z + xv.w*k3.z;
            acck[i][3] += xv.x*k0.w + xv.y*k1.w + xv.z*k2.w + xv.w*k3.w;
            accv[i][0] += xv.x*v0.x + xv.y*v1.x + xv.z*v2.x + xv.w*v3.x;
            accv[i][1] += xv.x*v0.y + xv.y*v1.y + xv.z*v2.y + xv.w*v3.y;
            accv[i][2] += xv.x*v0.z + xv.y*v1.z + xv.z*v2.z + xv.w*v3.z;
            accv[i][3] += xv.x*v0.w + xv.y*v1.w + xv.z*v2.w + xv.w*v3.w;
        }
    }

    float4* outK4 = (float4*)outK;
    float4* outV4 = (float4*)outV;
    #pragma unroll
    for (int i = 0; i < 8; ++i) {
        outK4[(base + r0 + i) * 32 + eg] =
            make_float4(acck[i][0], acck[i][1], acck[i][2], acck[i][3]);
        outV4[(base + r0 + i) * 32 + eg] =
            make_float4(accv[i][0], accv[i][1], accv[i][2], accv[i][3]);
    }
}

// ---------------------------------------------------------------------------
// Attention: single-pass flash, 64 threads/block, 4 p-rows per thread so
// each K/V LDS read is amortized over 4 q-rows (LDS traffic /4 vs 1-row).
// One block per (b,h); XCD-aware remap keeps same-b blocks on one XCD.
// q prescaled by 1/sqrt(D) at load.
// ---------------------------------------------------------------------------
__global__ __launch_bounds__(64, 1) void attn_kernel(
    const float* __restrict__ q, const float* __restrict__ k,
    const float* __restrict__ v, const float* __restrict__ mask,
    float* __restrict__ out)
{
    __shared__ float4 ks[N][4];
    __shared__ float4 vs[N][4];
    const int raw = blockIdx.x;
    const int g = raw >> 6, rr6 = raw & 63;
    const int h = rr6 >> 3;
    const int b = g * 8 + (rr6 & 7);
    const int t = threadIdx.x;          // 0..63

    const float4* k4 = (const float4*)k;
    const float4* v4 = (const float4*)v;
    for (int idx = t; idx < N * 4; idx += 64) {
        int n = idx >> 2, c = idx & 3;
        size_t off = (size_t)(b * N + n) * 32 + h * 4 + c;
        ks[n][c] = k4[off];
        vs[n][c] = v4[off];
    }
    __syncthreads();

    // load q for 4 rows (p = t + 64*r), prescaled by 1/sqrt(D)
    float4 qv[4][4];
    int prow[4];
    bool act[4];
    #pragma unroll
    for (int r = 0; r < 4; ++r) {
        prow[r] = t + 64 * r;
        act[r] = prow[r] < P;
        int pc = act[r] ? prow[r] : 0;
        const float4* qr = (const float4*)q + (size_t)(b * P + pc) * 32 + h * 4;
        #pragma unroll
        for (int c = 0; c < 4; ++c) {
            float4 x = qr[c];
            qv[r][c] = make_float4(x.x*INV_SQRT_D, x.y*INV_SQRT_D,
                                   x.z*INV_SQRT_D, x.w*INV_SQRT_D);
        }
    }

    float m2[4], l[4], o[4][16];
    #pragma unroll
    for (int r = 0; r < 4; ++r) {
        m2[r] = -INFINITY; l[r] = 0.f;
        #pragma unroll
        for (int d = 0; d < 16; ++d) o[r][d] = 0.f;
    }

    const float4* mk4 = (const float4*)mask;
    size_t mrow[4];
    #pragma unroll
    for (int r = 0; r < 4; ++r)
        mrow[r] = (size_t)(b * P + (act[r] ? prow[r] : 0)) * (N / 4);

    for (int t0 = 0; t0 < N; t0 += 8) {       // 25 exact tiles
        const int q4 = t0 >> 2;
        // prefetch mask tile for all 4 rows
        float4 mva[4], mvb[4];
        #pragma unroll
        for (int r = 0; r < 4; ++r) {
            mva[r] = mk4[mrow[r] + q4];
            mvb[r] = mk4[mrow[r] + q4 + 1];
        }
        // QK^T dots: K[n] read once, used by 4 rows
        float s[4][8];
        #pragma unroll
        for (int j = 0; j < 8; ++j) {
            int n = t0 + j;
            float4 k0 = ks[n][0], k1 = ks[n][1], k2 = ks[n][2], k3 = ks[n][3];
            #pragma unroll
            for (int r = 0; r < 4; ++r)
                s[r][j] = dot4(qv[r][0], k0) + dot4(qv[r][1], k1) +
                          dot4(qv[r][2], k2) + dot4(qv[r][3], k3);
        }
        // per-row online softmax finish
        #pragma unroll
        for (int r = 0; r < 4; ++r) {
            float mvf[8] = {mva[r].x, mva[r].y, mva[r].z, mva[r].w,
                            mvb[r].x, mvb[r].y, mvb[r].z, mvb[r].w};
            float tmax = -INFINITY;
            #pragma unroll
            for (int j = 0; j < 8; ++j) {
                s[r][j] += mvf[j];
                tmax = fmaxf(tmax, s[r][j]);
            }
            float nm = fmaxf(m2[r], tmax);
            if (nm == -INFINITY) {            // fully masked so far
                #pragma unroll
                for (int j = 0; j < 8; ++j) s[r][j] = 0.f;
                continue;
            }
            float scale = (m2[r] == -INFINITY) ? 0.f : __expf(m2[r] - nm);
            l[r] *= scale;
            #pragma unroll
            for (int d = 0; d < 16; ++d) o[r][d] *= scale;
            #pragma unroll
            for (int j = 0; j < 8; ++j) {
                float w = __expf(s[r][j] - nm);
                s[r][j] = w;
                l[r] += w;
            }
            m2[r] = nm;
        }
        // PV: V[n] read once, used by 4 rows
        #pragma unroll
        for (int j = 0; j < 8; ++j) {
            int n = t0 + j;
            float4 v0 = vs[n][0], v1 = vs[n][1], v2 = vs[n][2], v3 = vs[n][3];
            #pragma unroll
            for (int r = 0; r < 4; ++r) {
                float w = s[r][j];
                o[r][0]  += w*v0.x; o[r][1]  += w*v0.y; o[r][2]  += w*v0.z; o[r][3]  += w*v0.w;
                o[r][4]  += w*v1.x; o[r][5]  += w*v1.y; o[r][6]  += w*v1.z; o[r][7]  += w*v1.w;
                o[r][8]  += w*v2.x; o[r][9]  += w*v2.y; o[r][10] += w*v2.z; o[r][11] += w*v2.w;
                o[r][12] += w*v3.x; o[r][13] += w*v3.y; o[r][14] += w*v3.z; o[r][15] += w*v3.w;
            }
        }
    }

    float4* out4 = (float4*)out;
    #pragma unroll
    for (int r = 0; r < 4; ++r) {
        if (!act[r]) continue;
        float inv_l = 1.f / l[r];
        size_t ob = (size_t)(b * P + prow[r]) * 32 + h * 4;
        #pragma unroll
        for (int c = 0; c < 4; ++c)
            out4[ob + c] = make_float4(o[r][c*4]*inv_l, o[r][c*4+1]*inv_l,
                                       o[r][c*4+2]*inv_l, o[r][c*4+3]*inv_l);
    }
}

// ---------------------------------------------------------------------------
// Pointer scores + logits: sc = mh[b] @ nodes[b]^T, fused tanh/bias/mask.
// 64x64 tile per block, thread tile 4x4 (interleaved, stride 16).
// ---------------------------------------------------------------------------
__global__ __launch_bounds__(256) void pointer_kernel(
    const float* __restrict__ mh, const float* __restrict__ nodes,
    const float* __restrict__ mask, const int* __restrict__ gid,
    const int* __restrict__ cmp, const float* __restrict__ btab,
    float* __restrict__ out)
{
    __shared__ float4 ns[64][33];     // nodes tile, padded (132 floats/row)
    const int b = blockIdx.z;
    const int p_base = blockIdx.y * 64;
    const int n_base = blockIdx.x * 64;
    const int tid = threadIdx.x;
    const int pi = tid >> 4;          // 0..15
    const int ni = tid & 15;          // 0..15

    const float4* nodes4 = (const float4*)nodes;
    for (int idx = tid; idx < 64 * 32; idx += 256) {
        int r = idx >> 5, c = idx & 31;
        float4 val = make_float4(0.f, 0.f, 0.f, 0.f);
        if (n_base + r < N) val = nodes4[(size_t)(b * N + n_base + r) * 32 + c];
        ns[r][c] = val;
    }
    __syncthreads();

    float acc[4][4];
    #pragma unroll
    for (int i = 0; i < 4; ++i)
        #pragma unroll
        for (int j = 0; j < 4; ++j) acc[i][j] = 0.f;

    const float4* mh4 = (const float4*)mh;
    for (int c4 = 0; c4 < 32; ++c4) {
        float4 a[4];
        #pragma unroll
        for (int i = 0; i < 4; ++i) {
            int p = p_base + pi + 16 * i;
            int pr = p < P ? p : P - 1;
            a[i] = mh4[(size_t)(b * P + pr) * 32 + c4];
        }
        #pragma unroll
        for (int j = 0; j < 4; ++j) {
            float4 w = ns[ni + 16 * j][c4];
            #pragma unroll
            for (int i = 0; i < 4; ++i)
                acc[i][j] += dot4(a[i], w);
        }
    }

    float bt[MAX_DELTA + 1];
    #pragma unroll
    for (int t = 0; t <= MAX_DELTA; ++t) bt[t] = btab[t];

    #pragma unroll
    for (int i = 0; i < 4; ++i) {
        int p = p_base + pi + 16 * i;
        if (p >= P) continue;
        int cm = cmp[b * P + p];
        #pragma unroll
        for (int j = 0; j < 4; ++j) {
            int n = n_base + ni + 16 * j;
            if (n >= N) continue;
            int g = gid[b * N + n];
            int delta = g - cm;
            delta = delta < 0 ? 0 : (delta > MAX_DELTA ? MAX_DELTA : delta);
            float mv = mask[(size_t)(b * P + p) * N + n];
            float pb = isfinite(mv) ? bt[delta] : 0.f;
            float logit = LOGIT_CLIP * tanhf(acc[i][j] * INV_SQRT_E) + pb + mv;
            out[(size_t)(b * P + p) * N + n] = logit;
        }
    }
}

// ---------------------------------------------------------------------------
// Top-k (k=20) + temperature + renormalize, in place on d_out.
// One wave per row. Radix-select (32 ballot steps) finds the exact 20th
// largest value T; selection = {x > T} + {x == T, lowest index} (same
// tie-break as jax.lax.top_k). Softmax over selected relative to T.
// ---------------------------------------------------------------------------
__global__ __launch_bounds__(256) void topk_kernel(float* __restrict__ io)
{
    const int wv = threadIdx.x >> 6, lane = threadIdx.x & 63;
    const long row = (long)blockIdx.x * 4 + wv;
    float* r = io + row * N;

    float x[4];
    unsigned u[4];
    #pragma unroll
    for (int j = 0; j < 4; ++j) {
        int n = lane + 64 * j;
        bool valid = n < N;
        x[j] = valid ? r[n] : -INFINITY;
        unsigned bb = __float_as_uint(x[j]);
        // orderable mapping: larger float <-> larger uint; invalid -> 0 (min)
        u[j] = valid ? ((bb & 0x80000000u) ? ~bb : (bb | 0x80000000u)) : 0u;
    }

    // radix-select: after the loop, p == orderable(20th largest value)
    unsigned p = 0;
    for (int i = 31; i >= 0; --i) {
        unsigned c = p | (1u << i);
        int cnt = 0;
        #pragma unroll
        for (int j = 0; j < 4; ++j)
            cnt += (int)__popcll(__ballot(u[j] >= c));
        if (cnt >= TOP_K) p = c;
    }

    // elements strictly above threshold
    int cnt_gt = 0;
    #pragma unroll
    for (int j = 0; j < 4; ++j)
        cnt_gt += (int)__popcll(__ballot(u[j] > p));
    const int needed = TOP_K - cnt_gt;

    // select ties (u == p) in index order (n = lane + 64*j -> j-major)
    const unsigned long long lt_mask = (1ull << lane) - 1ull;
    bool sel[4];
    int eq_before = 0;
    #pragma unroll
    for (int j = 0; j < 4; ++j) {
        unsigned long long em = __ballot(u[j] == p);
        int myrank = eq_before + (int)__popcll(em & lt_mask);
        sel[j] = (u[j] > p) || ((u[j] == p) && (myrank < needed));
        eq_before += (int)__popcll(em);
    }

    // invert orderable mapping to get threshold as float
    unsigned tb = (p & 0x80000000u) ? (p & 0x7FFFFFFFu) : ~p;
    float Tf = __uint_as_float(tb);

    float e[4];
    float sum = 0.f;
    if (isfinite(Tf)) {
        #pragma unroll
        for (int j = 0; j < 4; ++j) {
            e[j] = sel[j] ? __expf((x[j] - Tf) * INV_TEMP) : 0.f;
            sum += e[j];
        }
    } else {
        // fully-masked row: selected entries are equal -> uniform weights
        #pragma unroll
        for (int j = 0; j < 4; ++j) {
            e[j] = sel[j] ? 1.f : 0.f;
            sum += e[j];
        }
    }
    #pragma unroll
    for (int off = 32; off > 0; off >>= 1) sum += __shfl_xor(sum, off);
    float inv = 1.f / sum;
    #pragma unroll
    for (int j = 0; j < 4; ++j) {
        int n = lane + 64 * j;
        if (n < N) r[n] = e[j] * inv;
    }
}

// ---------------------------------------------------------------------------
extern "C" void kernel_launch(void* const* d_in, const int* in_sizes, int n_in,
                              void* d_out, int out_size, void* d_ws, size_t ws_size,
                              hipStream_t stream) {
    const float* nodes = (const float*)d_in[0];
    const float* first = (const float*)d_in[1];
    const float* last  = (const float*)d_in[2];
    const float* mask  = (const float*)d_in[3];
    const int*   gid   = (const int*)d_in[4];
    const int*   cmp   = (const int*)d_in[5];
    const float* Wqf   = (const float*)d_in[6];
    const float* Wql   = (const float*)d_in[7];
    const float* Wk    = (const float*)d_in[8];
    const float* Wv    = (const float*)d_in[9];
    const float* Wc    = (const float*)d_in[10];
    const float* bc    = (const float*)d_in[11];
    const float* btab  = (const float*)d_in[12];
    float* out = (float*)d_out;

    float* ws   = (float*)d_ws;
    const size_t SLOT = (size_t)B * P * E;   // 6,553,600 floats
    float* qb  = ws;                 // q, later reused for mh
    float* kb  = ws + SLOT;
    float* vb  = ws + 2 * SLOT;
    float* ao  = ws + 3 * SLOT;      // attention output (concat heads)

    const int M = B * P;             // 51200 rows (= B*N too)

    // q = first@Wqf + last@Wql ; {k,v} = nodes@{Wk,Wv} fused
    proj_kernel<<<M / 64, 256, 0, stream>>>(first, Wqf, last, Wql, nullptr, qb);
    kv_proj_kernel<<<M / 64, 256, 0, stream>>>(nodes, Wk, Wv, kb, vb);

    // masked MHA (single-pass flash, 4 rows/thread, XCD-aware remap)
    attn_kernel<<<B * H, 64, 0, stream>>>(qb, kb, vb, mask, ao);

    // mh = ao @ Wc + bc   (into q's slot — q is dead now)
    proj_kernel<<<M / 64, 256, 0, stream>>>(ao, Wc, nullptr, nullptr, bc, qb);

    // pointer logits into d_out
    dim3 pgrid((N + 63) / 64, (P + 63) / 64, B);
    pointer_kernel<<<pgrid, 256, 0, stream>>>(qb, nodes, mask, gid, cmp, btab, out);

    // top-k + renormalize in place
    topk_kernel<<<(B * P) / 4, 256, 0, stream>>>(out);
}

// Round 6
// 622.486 us; speedup vs baseline: 1.5345x; 1.0861x over previous
//
#include <hip/hip_runtime.h>
#include <hip/hip_bf16.h>
#include <math.h>

// Problem constants (fixed by setup_inputs)
constexpr int B = 256, P = 200, N = 200, E = 128, H = 8, D = 16;
constexpr float INV_SQRT_D = 0.25f;              // 1/sqrt(16)
constexpr float INV_SQRT_E = 0.08838834764831845f; // 1/sqrt(128)
constexpr float LOGIT_CLIP = 10.0f;
constexpr float INV_TEMP = 1.25f;                // 1/0.8
constexpr int TOP_K = 20;
constexpr int MAX_DELTA = 4;

__device__ __forceinline__ float dot4(float4 a, float4 b) {
    return a.x*b.x + a.y*b.y + a.z*b.z + a.w*b.w;
}

// ---------------------------------------------------------------------------
// GEMM: out[M,128] = X1[M,128] @ W1[128,128] (+ X2 @ W2) (+ bias)
// tile 64 rows x 128 cols per 256-thread block, thread tile 8x4
// ---------------------------------------------------------------------------
__global__ __launch_bounds__(256) void proj_kernel(
    const float* __restrict__ X1, const float* __restrict__ W1,
    const float* __restrict__ X2, const float* __restrict__ W2,
    const float* __restrict__ bias, float* __restrict__ out)
{
    __shared__ float4 xs[64][32];      // 64 rows x 128 floats
    const int tid = threadIdx.x;
    const int eg = tid & 31;           // column group: e = eg*4..eg*4+3
    const int rg = tid >> 5;           // 0..7
    const int r0 = rg * 8;             // rows r0..r0+7
    const long base = (long)blockIdx.x * 64;

    float acc[8][4];
    #pragma unroll
    for (int i = 0; i < 8; ++i)
        #pragma unroll
        for (int j = 0; j < 4; ++j) acc[i][j] = 0.f;

    for (int pass = 0; pass < 2; ++pass) {
        const float* X = pass ? X2 : X1;
        const float* W = pass ? W2 : W1;
        if (!X) break;
        if (pass) __syncthreads();
        const float4* X4 = (const float4*)X;
        for (int idx = tid; idx < 64 * 32; idx += 256) {
            int r = idx >> 5, c = idx & 31;
            xs[r][c] = X4[(base + r) * 32 + c];
        }
        __syncthreads();
        for (int c4 = 0; c4 < 32; ++c4) {
            float4 w0 = *(const float4*)&W[(c4*4+0)*128 + eg*4];
            float4 w1 = *(const float4*)&W[(c4*4+1)*128 + eg*4];
            float4 w2 = *(const float4*)&W[(c4*4+2)*128 + eg*4];
            float4 w3 = *(const float4*)&W[(c4*4+3)*128 + eg*4];
            #pragma unroll
            for (int i = 0; i < 8; ++i) {
                float4 xv = xs[r0 + i][c4];
                acc[i][0] += xv.x*w0.x + xv.y*w1.x + xv.z*w2.x + xv.w*w3.x;
                acc[i][1] += xv.x*w0.y + xv.y*w1.y + xv.z*w2.y + xv.w*w3.y;
                acc[i][2] += xv.x*w0.z + xv.y*w1.z + xv.z*w2.z + xv.w*w3.z;
                acc[i][3] += xv.x*w0.w + xv.y*w1.w + xv.z*w2.w + xv.w*w3.w;
            }
        }
    }

    float4 bv = make_float4(0.f, 0.f, 0.f, 0.f);
    if (bias) bv = *(const float4*)&bias[eg*4];
    float4* out4 = (float4*)out;
    #pragma unroll
    for (int i = 0; i < 8; ++i) {
        out4[(base + r0 + i) * 32 + eg] =
            make_float4(acc[i][0]+bv.x, acc[i][1]+bv.y, acc[i][2]+bv.z, acc[i][3]+bv.w);
    }
}

// ---------------------------------------------------------------------------
// Fused K+V projection: stage X tile once, compute X@Wk and X@Wv.
// ---------------------------------------------------------------------------
__global__ __launch_bounds__(256) void kv_proj_kernel(
    const float* __restrict__ X, const float* __restrict__ Wk,
    const float* __restrict__ Wv, float* __restrict__ outK,
    float* __restrict__ outV)
{
    __shared__ float4 xs[64][32];
    const int tid = threadIdx.x;
    const int eg = tid & 31;
    const int rg = tid >> 5;
    const int r0 = rg * 8;
    const long base = (long)blockIdx.x * 64;

    float acck[8][4], accv[8][4];
    #pragma unroll
    for (int i = 0; i < 8; ++i)
        #pragma unroll
        for (int j = 0; j < 4; ++j) { acck[i][j] = 0.f; accv[i][j] = 0.f; }

    const float4* X4 = (const float4*)X;
    for (int idx = tid; idx < 64 * 32; idx += 256) {
        int r = idx >> 5, c = idx & 31;
        xs[r][c] = X4[(base + r) * 32 + c];
    }
    __syncthreads();

    for (int c4 = 0; c4 < 32; ++c4) {
        float4 k0 = *(const float4*)&Wk[(c4*4+0)*128 + eg*4];
        float4 k1 = *(const float4*)&Wk[(c4*4+1)*128 + eg*4];
        float4 k2 = *(const float4*)&Wk[(c4*4+2)*128 + eg*4];
        float4 k3 = *(const float4*)&Wk[(c4*4+3)*128 + eg*4];
        float4 v0 = *(const float4*)&Wv[(c4*4+0)*128 + eg*4];
        float4 v1 = *(const float4*)&Wv[(c4*4+1)*128 + eg*4];
        float4 v2 = *(const float4*)&Wv[(c4*4+2)*128 + eg*4];
        float4 v3 = *(const float4*)&Wv[(c4*4+3)*128 + eg*4];
        #pragma unroll
        for (int i = 0; i < 8; ++i) {
            float4 xv = xs[r0 + i][c4];
            acck[i][0] += xv.x*k0.x + xv.y*k1.x + xv.z*k2.x + xv.w*k3.x;
            acck[i][1] += xv.x*k0.y + xv.y*k1.y + xv.z*k2.y + xv.w*k3.y;
            acck[i][2] += xv.x*k0.z + xv.y*k1.z + xv.z*k2.z + xv.w*k3.z;
            acck[i][3] += xv.x*k0.w + xv.y*k1.w + xv.z*k2.w + xv.w*k3.w;
            accv[i][0] += xv.x*v0.x + xv.y*v1.x + xv.z*v2.x + xv.w*v3.x;
            accv[i][1] += xv.x*v0.y + xv.y*v1.y + xv.z*v2.y + xv.w*v3.y;
            accv[i][2] += xv.x*v0.z + xv.y*v1.z + xv.z*v2.z + xv.w*v3.z;
            accv[i][3] += xv.x*v0.w + xv.y*v1.w + xv.z*v2.w + xv.w*v3.w;
        }
    }

    float4* outK4 = (float4*)outK;
    float4* outV4 = (float4*)outV;
    #pragma unroll
    for (int i = 0; i < 8; ++i) {
        outK4[(base + r0 + i) * 32 + eg] =
            make_float4(acck[i][0], acck[i][1], acck[i][2], acck[i][3]);
        outV4[(base + r0 + i) * 32 + eg] =
            make_float4(accv[i][0], accv[i][1], accv[i][2], accv[i][3]);
    }
}

// ---------------------------------------------------------------------------
// Attention: bound-softmax single pass. One block (256 thr) per (b,h);
// thread p owns one q-row. No online rescaling: M = |q|*max|k| >= every
// score+mask (mask <= 0), so w = exp(s+mask-M) in (0,1], l = sum w,
// out = (sum w*v)/l — ratios identical to softmax (offset cancels).
// exp(-inf) = 0 handles masked entries branch-free.
// XCD-aware remap keeps same-b blocks on one XCD (mask/k/v L2 reuse).
// ---------------------------------------------------------------------------
__global__ __launch_bounds__(256) void attn_kernel(
    const float* __restrict__ q, const float* __restrict__ k,
    const float* __restrict__ v, const float* __restrict__ mask,
    float* __restrict__ out)
{
    __shared__ float4 ks[N][4];
    __shared__ float4 vs[N][4];
    __shared__ float red[4];
    const int raw = blockIdx.x;
    const int g = raw >> 6, rr6 = raw & 63;
    const int h = rr6 >> 3;
    const int b = g * 8 + (rr6 & 7);
    const int tid = threadIdx.x;

    const float4* k4 = (const float4*)k;
    const float4* v4 = (const float4*)v;
    for (int idx = tid; idx < N * 4; idx += 256) {
        int n = idx >> 2, c = idx & 3;
        size_t off = (size_t)(b * N + n) * 32 + h * 4 + c;
        ks[n][c] = k4[off];
        vs[n][c] = v4[off];
    }
    __syncthreads();

    // kmax2 = max_n |k_n|^2 (block-wide, one time)
    float nrm = 0.f;
    if (tid < N) {
        float4 a0 = ks[tid][0], a1 = ks[tid][1], a2 = ks[tid][2], a3 = ks[tid][3];
        nrm = dot4(a0,a0) + dot4(a1,a1) + dot4(a2,a2) + dot4(a3,a3);
    }
    float wm = nrm;
    #pragma unroll
    for (int off = 32; off > 0; off >>= 1) wm = fmaxf(wm, __shfl_xor(wm, off));
    if ((tid & 63) == 0) red[tid >> 6] = wm;
    __syncthreads();
    const float kmax2 = fmaxf(fmaxf(red[0], red[1]), fmaxf(red[2], red[3]));

    const int p = tid;
    if (p >= P) return;

    // q prescaled by 1/sqrt(D)
    const float4* qr = (const float4*)q + (size_t)(b * P + p) * 32 + h * 4;
    float4 q0 = qr[0], q1 = qr[1], q2 = qr[2], q3 = qr[3];
    q0.x*=INV_SQRT_D; q0.y*=INV_SQRT_D; q0.z*=INV_SQRT_D; q0.w*=INV_SQRT_D;
    q1.x*=INV_SQRT_D; q1.y*=INV_SQRT_D; q1.z*=INV_SQRT_D; q1.w*=INV_SQRT_D;
    q2.x*=INV_SQRT_D; q2.y*=INV_SQRT_D; q2.z*=INV_SQRT_D; q2.w*=INV_SQRT_D;
    q3.x*=INV_SQRT_D; q3.y*=INV_SQRT_D; q3.z*=INV_SQRT_D; q3.w*=INV_SQRT_D;
    const float qn2 = dot4(q0,q0) + dot4(q1,q1) + dot4(q2,q2) + dot4(q3,q3);
    const float M = sqrtf(qn2 * kmax2);   // >= any |q.k| (Cauchy-Schwarz)

    const float4* m4 = (const float4*)(mask + (size_t)(b * P + p) * N);

    float l = 0.f;
    float o[16];
    #pragma unroll
    for (int d = 0; d < 16; ++d) o[d] = 0.f;

    #pragma unroll 2
    for (int n4 = 0; n4 < N / 4; ++n4) {
        float4 mv = m4[n4];
        float mvf[4] = {mv.x, mv.y, mv.z, mv.w};
        #pragma unroll
        for (int j = 0; j < 4; ++j) {
            int n = n4 * 4 + j;
            float s = dot4(q0, ks[n][0]) + dot4(q1, ks[n][1]) +
                      dot4(q2, ks[n][2]) + dot4(q3, ks[n][3]);
            float w = __expf(s + mvf[j] - M);
            l += w;
            float4 v0 = vs[n][0], v1 = vs[n][1], v2 = vs[n][2], v3 = vs[n][3];
            o[0]  += w*v0.x; o[1]  += w*v0.y; o[2]  += w*v0.z; o[3]  += w*v0.w;
            o[4]  += w*v1.x; o[5]  += w*v1.y; o[6]  += w*v1.z; o[7]  += w*v1.w;
            o[8]  += w*v2.x; o[9]  += w*v2.y; o[10] += w*v2.z; o[11] += w*v2.w;
            o[12] += w*v3.x; o[13] += w*v3.y; o[14] += w*v3.z; o[15] += w*v3.w;
        }
    }

    float inv_l = 1.f / l;
    float4* out4 = (float4*)out;
    size_t ob = (size_t)(b * P + p) * 32 + h * 4;
    #pragma unroll
    for (int c = 0; c < 4; ++c)
        out4[ob + c] = make_float4(o[c*4]*inv_l, o[c*4+1]*inv_l,
                                   o[c*4+2]*inv_l, o[c*4+3]*inv_l);
}

// ---------------------------------------------------------------------------
// Pointer scores + logits: sc = mh[b] @ nodes[b]^T, fused tanh/bias/mask.
// 64x64 tile per block, thread tile 4x4 (interleaved, stride 16).
// ---------------------------------------------------------------------------
__global__ __launch_bounds__(256) void pointer_kernel(
    const float* __restrict__ mh, const float* __restrict__ nodes,
    const float* __restrict__ mask, const int* __restrict__ gid,
    const int* __restrict__ cmp, const float* __restrict__ btab,
    float* __restrict__ out)
{
    __shared__ float4 ns[64][33];     // nodes tile, padded (132 floats/row)
    const int b = blockIdx.z;
    const int p_base = blockIdx.y * 64;
    const int n_base = blockIdx.x * 64;
    const int tid = threadIdx.x;
    const int pi = tid >> 4;          // 0..15
    const int ni = tid & 15;          // 0..15

    const float4* nodes4 = (const float4*)nodes;
    for (int idx = tid; idx < 64 * 32; idx += 256) {
        int r = idx >> 5, c = idx & 31;
        float4 val = make_float4(0.f, 0.f, 0.f, 0.f);
        if (n_base + r < N) val = nodes4[(size_t)(b * N + n_base + r) * 32 + c];
        ns[r][c] = val;
    }
    __syncthreads();

    float acc[4][4];
    #pragma unroll
    for (int i = 0; i < 4; ++i)
        #pragma unroll
        for (int j = 0; j < 4; ++j) acc[i][j] = 0.f;

    const float4* mh4 = (const float4*)mh;
    for (int c4 = 0; c4 < 32; ++c4) {
        float4 a[4];
        #pragma unroll
        for (int i = 0; i < 4; ++i) {
            int p = p_base + pi + 16 * i;
            int pr = p < P ? p : P - 1;
            a[i] = mh4[(size_t)(b * P + pr) * 32 + c4];
        }
        #pragma unroll
        for (int j = 0; j < 4; ++j) {
            float4 w = ns[ni + 16 * j][c4];
            #pragma unroll
            for (int i = 0; i < 4; ++i)
                acc[i][j] += dot4(a[i], w);
        }
    }

    float bt[MAX_DELTA + 1];
    #pragma unroll
    for (int t = 0; t <= MAX_DELTA; ++t) bt[t] = btab[t];

    #pragma unroll
    for (int i = 0; i < 4; ++i) {
        int p = p_base + pi + 16 * i;
        if (p >= P) continue;
        int cm = cmp[b * P + p];
        #pragma unroll
        for (int j = 0; j < 4; ++j) {
            int n = n_base + ni + 16 * j;
            if (n >= N) continue;
            int g = gid[b * N + n];
            int delta = g - cm;
            delta = delta < 0 ? 0 : (delta > MAX_DELTA ? MAX_DELTA : delta);
            float mv = mask[(size_t)(b * P + p) * N + n];
            float pb = isfinite(mv) ? bt[delta] : 0.f;
            float logit = LOGIT_CLIP * tanhf(acc[i][j] * INV_SQRT_E) + pb + mv;
            out[(size_t)(b * P + p) * N + n] = logit;
        }
    }
}

// ---------------------------------------------------------------------------
// Top-k (k=20) + temperature + renormalize, in place on d_out.
// One wave per row. Radix-select (32 ballot steps) finds the exact 20th
// largest value T; selection = {x > T} + {x == T, lowest index} (same
// tie-break as jax.lax.top_k). Softmax over selected relative to T.
// ---------------------------------------------------------------------------
__global__ __launch_bounds__(256) void topk_kernel(float* __restrict__ io)
{
    const int wv = threadIdx.x >> 6, lane = threadIdx.x & 63;
    const long row = (long)blockIdx.x * 4 + wv;
    float* r = io + row * N;

    float x[4];
    unsigned u[4];
    #pragma unroll
    for (int j = 0; j < 4; ++j) {
        int n = lane + 64 * j;
        bool valid = n < N;
        x[j] = valid ? r[n] : -INFINITY;
        unsigned bb = __float_as_uint(x[j]);
        // orderable mapping: larger float <-> larger uint; invalid -> 0 (min)
        u[j] = valid ? ((bb & 0x80000000u) ? ~bb : (bb | 0x80000000u)) : 0u;
    }

    // radix-select: after the loop, p == orderable(20th largest value)
    unsigned p = 0;
    for (int i = 31; i >= 0; --i) {
        unsigned c = p | (1u << i);
        int cnt = 0;
        #pragma unroll
        for (int j = 0; j < 4; ++j)
            cnt += (int)__popcll(__ballot(u[j] >= c));
        if (cnt >= TOP_K) p = c;
    }

    // elements strictly above threshold
    int cnt_gt = 0;
    #pragma unroll
    for (int j = 0; j < 4; ++j)
        cnt_gt += (int)__popcll(__ballot(u[j] > p));
    const int needed = TOP_K - cnt_gt;

    // select ties (u == p) in index order (n = lane + 64*j -> j-major)
    const unsigned long long lt_mask = (1ull << lane) - 1ull;
    bool sel[4];
    int eq_before = 0;
    #pragma unroll
    for (int j = 0; j < 4; ++j) {
        unsigned long long em = __ballot(u[j] == p);
        int myrank = eq_before + (int)__popcll(em & lt_mask);
        sel[j] = (u[j] > p) || ((u[j] == p) && (myrank < needed));
        eq_before += (int)__popcll(em);
    }

    // invert orderable mapping to get threshold as float
    unsigned tb = (p & 0x80000000u) ? (p & 0x7FFFFFFFu) : ~p;
    float Tf = __uint_as_float(tb);

    float e[4];
    float sum = 0.f;
    if (isfinite(Tf)) {
        #pragma unroll
        for (int j = 0; j < 4; ++j) {
            e[j] = sel[j] ? __expf((x[j] - Tf) * INV_TEMP) : 0.f;
            sum += e[j];
        }
    } else {
        // fully-masked row: selected entries are equal -> uniform weights
        #pragma unroll
        for (int j = 0; j < 4; ++j) {
            e[j] = sel[j] ? 1.f : 0.f;
            sum += e[j];
        }
    }
    #pragma unroll
    for (int off = 32; off > 0; off >>= 1) sum += __shfl_xor(sum, off);
    float inv = 1.f / sum;
    #pragma unroll
    for (int j = 0; j < 4; ++j) {
        int n = lane + 64 * j;
        if (n < N) r[n] = e[j] * inv;
    }
}

// ---------------------------------------------------------------------------
extern "C" void kernel_launch(void* const* d_in, const int* in_sizes, int n_in,
                              void* d_out, int out_size, void* d_ws, size_t ws_size,
                              hipStream_t stream) {
    const float* nodes = (const float*)d_in[0];
    const float* first = (const float*)d_in[1];
    const float* last  = (const float*)d_in[2];
    const float* mask  = (const float*)d_in[3];
    const int*   gid   = (const int*)d_in[4];
    const int*   cmp   = (const int*)d_in[5];
    const float* Wqf   = (const float*)d_in[6];
    const float* Wql   = (const float*)d_in[7];
    const float* Wk    = (const float*)d_in[8];
    const float* Wv    = (const float*)d_in[9];
    const float* Wc    = (const float*)d_in[10];
    const float* bc    = (const float*)d_in[11];
    const float* btab  = (const float*)d_in[12];
    float* out = (float*)d_out;

    float* ws   = (float*)d_ws;
    const size_t SLOT = (size_t)B * P * E;   // 6,553,600 floats
    float* qb  = ws;                 // q, later reused for mh
    float* kb  = ws + SLOT;
    float* vb  = ws + 2 * SLOT;
    float* ao  = ws + 3 * SLOT;      // attention output (concat heads)

    const int M = B * P;             // 51200 rows (= B*N too)

    // q = first@Wqf + last@Wql ; {k,v} = nodes@{Wk,Wv} fused
    proj_kernel<<<M / 64, 256, 0, stream>>>(first, Wqf, last, Wql, nullptr, qb);
    kv_proj_kernel<<<M / 64, 256, 0, stream>>>(nodes, Wk, Wv, kb, vb);

    // masked MHA (bound-softmax single pass, XCD-aware remap)
    attn_kernel<<<B * H, 256, 0, stream>>>(qb, kb, vb, mask, ao);

    // mh = ao @ Wc + bc   (into q's slot — q is dead now)
    proj_kernel<<<M / 64, 256, 0, stream>>>(ao, Wc, nullptr, nullptr, bc, qb);

    // pointer logits into d_out
    dim3 pgrid((N + 63) / 64, (P + 63) / 64, B);
    pointer_kernel<<<pgrid, 256, 0, stream>>>(qb, nodes, mask, gid, cmp, btab, out);

    // top-k + renormalize in place
    topk_kernel<<<(B * P) / 4, 256, 0, stream>>>(out);
}

// Round 7
// 610.402 us; speedup vs baseline: 1.5648x; 1.0198x over previous
//
#include <hip/hip_runtime.h>
#include <hip/hip_bf16.h>
#include <math.h>

// Problem constants (fixed by setup_inputs)
constexpr int B = 256, P = 200, N = 200, E = 128, H = 8, D = 16;
constexpr float INV_SQRT_D = 0.25f;              // 1/sqrt(16)
constexpr float INV_SQRT_E = 0.08838834764831845f; // 1/sqrt(128)
constexpr float LOGIT_CLIP = 10.0f;
constexpr float INV_TEMP = 1.25f;                // 1/0.8
constexpr int TOP_K = 20;
constexpr int MAX_DELTA = 4;

__device__ __forceinline__ float dot4(float4 a, float4 b) {
    return a.x*b.x + a.y*b.y + a.z*b.z + a.w*b.w;
}

// ---------------------------------------------------------------------------
// GEMM: out[M,128] = X1[M,128] @ W1[128,128] (+ X2 @ W2) (+ bias)
// tile 64 rows x 128 cols per 256-thread block, thread tile 8x4
// ---------------------------------------------------------------------------
__global__ __launch_bounds__(256) void proj_kernel(
    const float* __restrict__ X1, const float* __restrict__ W1,
    const float* __restrict__ X2, const float* __restrict__ W2,
    const float* __restrict__ bias, float* __restrict__ out)
{
    __shared__ float4 xs[64][32];      // 64 rows x 128 floats
    const int tid = threadIdx.x;
    const int eg = tid & 31;           // column group: e = eg*4..eg*4+3
    const int rg = tid >> 5;           // 0..7
    const int r0 = rg * 8;             // rows r0..r0+7
    const long base = (long)blockIdx.x * 64;

    float acc[8][4];
    #pragma unroll
    for (int i = 0; i < 8; ++i)
        #pragma unroll
        for (int j = 0; j < 4; ++j) acc[i][j] = 0.f;

    for (int pass = 0; pass < 2; ++pass) {
        const float* X = pass ? X2 : X1;
        const float* W = pass ? W2 : W1;
        if (!X) break;
        if (pass) __syncthreads();
        const float4* X4 = (const float4*)X;
        for (int idx = tid; idx < 64 * 32; idx += 256) {
            int r = idx >> 5, c = idx & 31;
            xs[r][c] = X4[(base + r) * 32 + c];
        }
        __syncthreads();
        for (int c4 = 0; c4 < 32; ++c4) {
            float4 w0 = *(const float4*)&W[(c4*4+0)*128 + eg*4];
            float4 w1 = *(const float4*)&W[(c4*4+1)*128 + eg*4];
            float4 w2 = *(const float4*)&W[(c4*4+2)*128 + eg*4];
            float4 w3 = *(const float4*)&W[(c4*4+3)*128 + eg*4];
            #pragma unroll
            for (int i = 0; i < 8; ++i) {
                float4 xv = xs[r0 + i][c4];
                acc[i][0] += xv.x*w0.x + xv.y*w1.x + xv.z*w2.x + xv.w*w3.x;
                acc[i][1] += xv.x*w0.y + xv.y*w1.y + xv.z*w2.y + xv.w*w3.y;
                acc[i][2] += xv.x*w0.z + xv.y*w1.z + xv.z*w2.z + xv.w*w3.z;
                acc[i][3] += xv.x*w0.w + xv.y*w1.w + xv.z*w2.w + xv.w*w3.w;
            }
        }
    }

    float4 bv = make_float4(0.f, 0.f, 0.f, 0.f);
    if (bias) bv = *(const float4*)&bias[eg*4];
    float4* out4 = (float4*)out;
    #pragma unroll
    for (int i = 0; i < 8; ++i) {
        out4[(base + r0 + i) * 32 + eg] =
            make_float4(acc[i][0]+bv.x, acc[i][1]+bv.y, acc[i][2]+bv.z, acc[i][3]+bv.w);
    }
}

// ---------------------------------------------------------------------------
// Fused K+V projection: stage X tile once, compute X@Wk and X@Wv.
// ---------------------------------------------------------------------------
__global__ __launch_bounds__(256) void kv_proj_kernel(
    const float* __restrict__ X, const float* __restrict__ Wk,
    const float* __restrict__ Wv, float* __restrict__ outK,
    float* __restrict__ outV)
{
    __shared__ float4 xs[64][32];
    const int tid = threadIdx.x;
    const int eg = tid & 31;
    const int rg = tid >> 5;
    const int r0 = rg * 8;
    const long base = (long)blockIdx.x * 64;

    float acck[8][4], accv[8][4];
    #pragma unroll
    for (int i = 0; i < 8; ++i)
        #pragma unroll
        for (int j = 0; j < 4; ++j) { acck[i][j] = 0.f; accv[i][j] = 0.f; }

    const float4* X4 = (const float4*)X;
    for (int idx = tid; idx < 64 * 32; idx += 256) {
        int r = idx >> 5, c = idx & 31;
        xs[r][c] = X4[(base + r) * 32 + c];
    }
    __syncthreads();

    for (int c4 = 0; c4 < 32; ++c4) {
        float4 k0 = *(const float4*)&Wk[(c4*4+0)*128 + eg*4];
        float4 k1 = *(const float4*)&Wk[(c4*4+1)*128 + eg*4];
        float4 k2 = *(const float4*)&Wk[(c4*4+2)*128 + eg*4];
        float4 k3 = *(const float4*)&Wk[(c4*4+3)*128 + eg*4];
        float4 v0 = *(const float4*)&Wv[(c4*4+0)*128 + eg*4];
        float4 v1 = *(const float4*)&Wv[(c4*4+1)*128 + eg*4];
        float4 v2 = *(const float4*)&Wv[(c4*4+2)*128 + eg*4];
        float4 v3 = *(const float4*)&Wv[(c4*4+3)*128 + eg*4];
        #pragma unroll
        for (int i = 0; i < 8; ++i) {
            float4 xv = xs[r0 + i][c4];
            acck[i][0] += xv.x*k0.x + xv.y*k1.x + xv.z*k2.x + xv.w*k3.x;
            acck[i][1] += xv.x*k0.y + xv.y*k1.y + xv.z*k2.y + xv.w*k3.y;
            acck[i][2] += xv.x*k0.z + xv.y*k1.z + xv.z*k2.z + xv.w*k3.z;
            acck[i][3] += xv.x*k0.w + xv.y*k1.w + xv.z*k2.w + xv.w*k3.w;
            accv[i][0] += xv.x*v0.x + xv.y*v1.x + xv.z*v2.x + xv.w*v3.x;
            accv[i][1] += xv.x*v0.y + xv.y*v1.y + xv.z*v2.y + xv.w*v3.y;
            accv[i][2] += xv.x*v0.z + xv.y*v1.z + xv.z*v2.z + xv.w*v3.z;
            accv[i][3] += xv.x*v0.w + xv.y*v1.w + xv.z*v2.w + xv.w*v3.w;
        }
    }

    float4* outK4 = (float4*)outK;
    float4* outV4 = (float4*)outV;
    #pragma unroll
    for (int i = 0; i < 8; ++i) {
        outK4[(base + r0 + i) * 32 + eg] =
            make_float4(acck[i][0], acck[i][1], acck[i][2], acck[i][3]);
        outV4[(base + r0 + i) * 32 + eg] =
            make_float4(accv[i][0], accv[i][1], accv[i][2], accv[i][3]);
    }
}

// ---------------------------------------------------------------------------
// Attention: bound-softmax single pass. One block (256 thr) per (b,h);
// thread p owns one q-row. No online rescaling: M = |q|*max|k| >= every
// score+mask (mask <= 0), so w = exp(s+mask-M) in (0,1], l = sum w,
// out = (sum w*v)/l — ratios identical to softmax (offset cancels).
// exp(-inf) = 0 handles masked entries branch-free.
// XCD-aware remap keeps same-b blocks on one XCD (mask/k/v L2 reuse).
// ---------------------------------------------------------------------------
__global__ __launch_bounds__(256) void attn_kernel(
    const float* __restrict__ q, const float* __restrict__ k,
    const float* __restrict__ v, const float* __restrict__ mask,
    float* __restrict__ out)
{
    __shared__ float4 ks[N][4];
    __shared__ float4 vs[N][4];
    __shared__ float red[4];
    const int raw = blockIdx.x;
    const int g = raw >> 6, rr6 = raw & 63;
    const int h = rr6 >> 3;
    const int b = g * 8 + (rr6 & 7);
    const int tid = threadIdx.x;

    const float4* k4 = (const float4*)k;
    const float4* v4 = (const float4*)v;
    for (int idx = tid; idx < N * 4; idx += 256) {
        int n = idx >> 2, c = idx & 3;
        size_t off = (size_t)(b * N + n) * 32 + h * 4 + c;
        ks[n][c] = k4[off];
        vs[n][c] = v4[off];
    }
    __syncthreads();

    // kmax2 = max_n |k_n|^2 (block-wide, one time)
    float nrm = 0.f;
    if (tid < N) {
        float4 a0 = ks[tid][0], a1 = ks[tid][1], a2 = ks[tid][2], a3 = ks[tid][3];
        nrm = dot4(a0,a0) + dot4(a1,a1) + dot4(a2,a2) + dot4(a3,a3);
    }
    float wm = nrm;
    #pragma unroll
    for (int off = 32; off > 0; off >>= 1) wm = fmaxf(wm, __shfl_xor(wm, off));
    if ((tid & 63) == 0) red[tid >> 6] = wm;
    __syncthreads();
    const float kmax2 = fmaxf(fmaxf(red[0], red[1]), fmaxf(red[2], red[3]));

    const int p = tid;
    if (p >= P) return;

    // q prescaled by 1/sqrt(D)
    const float4* qr = (const float4*)q + (size_t)(b * P + p) * 32 + h * 4;
    float4 q0 = qr[0], q1 = qr[1], q2 = qr[2], q3 = qr[3];
    q0.x*=INV_SQRT_D; q0.y*=INV_SQRT_D; q0.z*=INV_SQRT_D; q0.w*=INV_SQRT_D;
    q1.x*=INV_SQRT_D; q1.y*=INV_SQRT_D; q1.z*=INV_SQRT_D; q1.w*=INV_SQRT_D;
    q2.x*=INV_SQRT_D; q2.y*=INV_SQRT_D; q2.z*=INV_SQRT_D; q2.w*=INV_SQRT_D;
    q3.x*=INV_SQRT_D; q3.y*=INV_SQRT_D; q3.z*=INV_SQRT_D; q3.w*=INV_SQRT_D;
    const float qn2 = dot4(q0,q0) + dot4(q1,q1) + dot4(q2,q2) + dot4(q3,q3);
    const float M = sqrtf(qn2 * kmax2);   // >= any |q.k| (Cauchy-Schwarz)

    const float4* m4 = (const float4*)(mask + (size_t)(b * P + p) * N);

    float l = 0.f;
    float o[16];
    #pragma unroll
    for (int d = 0; d < 16; ++d) o[d] = 0.f;

    #pragma unroll 2
    for (int n4 = 0; n4 < N / 4; ++n4) {
        float4 mv = m4[n4];
        float mvf[4] = {mv.x, mv.y, mv.z, mv.w};
        #pragma unroll
        for (int j = 0; j < 4; ++j) {
            int n = n4 * 4 + j;
            float s = dot4(q0, ks[n][0]) + dot4(q1, ks[n][1]) +
                      dot4(q2, ks[n][2]) + dot4(q3, ks[n][3]);
            float w = __expf(s + mvf[j] - M);
            l += w;
            float4 v0 = vs[n][0], v1 = vs[n][1], v2 = vs[n][2], v3 = vs[n][3];
            o[0]  += w*v0.x; o[1]  += w*v0.y; o[2]  += w*v0.z; o[3]  += w*v0.w;
            o[4]  += w*v1.x; o[5]  += w*v1.y; o[6]  += w*v1.z; o[7]  += w*v1.w;
            o[8]  += w*v2.x; o[9]  += w*v2.y; o[10] += w*v2.z; o[11] += w*v2.w;
            o[12] += w*v3.x; o[13] += w*v3.y; o[14] += w*v3.z; o[15] += w*v3.w;
        }
    }

    float inv_l = 1.f / l;
    float4* out4 = (float4*)out;
    size_t ob = (size_t)(b * P + p) * 32 + h * 4;
    #pragma unroll
    for (int c = 0; c < 4; ++c)
        out4[ob + c] = make_float4(o[c*4]*inv_l, o[c*4+1]*inv_l,
                                   o[c*4+2]*inv_l, o[c*4+3]*inv_l);
}

// ---------------------------------------------------------------------------
// Pointer scores + logits: sc = mh[b] @ nodes[b]^T, fused tanh/bias/mask.
// Double-LDS GEMM: 64x64 tile, K in 2 steps of 64, BOTH operand tiles
// staged in LDS (kills the per-c4 global mh re-streaming of the old
// version). Thread tile 4x4 interleaved (stride 16). ~35 KB LDS.
// ---------------------------------------------------------------------------
__global__ __launch_bounds__(256) void pointer_kernel(
    const float* __restrict__ mh, const float* __restrict__ nodes,
    const float* __restrict__ mask, const int* __restrict__ gid,
    const int* __restrict__ cmp, const float* __restrict__ btab,
    float* __restrict__ out)
{
    __shared__ float4 as[64][17];     // mh tile:    64 p-rows x 64 k (pad 17)
    __shared__ float4 bs[64][17];     // nodes tile: 64 n-rows x 64 k (pad 17)
    const int b = blockIdx.z;
    const int p_base = blockIdx.y * 64;
    const int n_base = blockIdx.x * 64;
    const int tid = threadIdx.x;
    const int pi = tid >> 4;          // 0..15
    const int ni = tid & 15;          // 0..15

    const float4* mh4 = (const float4*)mh;
    const float4* nodes4 = (const float4*)nodes;

    float acc[4][4];
    #pragma unroll
    for (int i = 0; i < 4; ++i)
        #pragma unroll
        for (int j = 0; j < 4; ++j) acc[i][j] = 0.f;

    for (int ks = 0; ks < 2; ++ks) {
        if (ks) __syncthreads();
        // stage: 64 rows x 16 float4 each array; 4 float4 per thread per array
        #pragma unroll
        for (int t = 0; t < 4; ++t) {
            int idx = tid + 256 * t;
            int r = idx >> 4, c = idx & 15;
            int pr = p_base + r; pr = pr < P ? pr : P - 1;
            int nr = n_base + r; nr = nr < N ? nr : N - 1;
            as[r][c] = mh4[(size_t)(b * P + pr) * 32 + ks * 16 + c];
            bs[r][c] = nodes4[(size_t)(b * N + nr) * 32 + ks * 16 + c];
        }
        __syncthreads();

        for (int c4 = 0; c4 < 16; ++c4) {
            float4 a[4], w[4];
            #pragma unroll
            for (int i = 0; i < 4; ++i) a[i] = as[pi + 16 * i][c4];
            #pragma unroll
            for (int j = 0; j < 4; ++j) w[j] = bs[ni + 16 * j][c4];
            #pragma unroll
            for (int i = 0; i < 4; ++i)
                #pragma unroll
                for (int j = 0; j < 4; ++j)
                    acc[i][j] += dot4(a[i], w[j]);
        }
    }

    float bt[MAX_DELTA + 1];
    #pragma unroll
    for (int t = 0; t <= MAX_DELTA; ++t) bt[t] = btab[t];

    #pragma unroll
    for (int i = 0; i < 4; ++i) {
        int p = p_base + pi + 16 * i;
        if (p >= P) continue;
        int cm = cmp[b * P + p];
        #pragma unroll
        for (int j = 0; j < 4; ++j) {
            int n = n_base + ni + 16 * j;
            if (n >= N) continue;
            int g = gid[b * N + n];
            int delta = g - cm;
            delta = delta < 0 ? 0 : (delta > MAX_DELTA ? MAX_DELTA : delta);
            float mv = mask[(size_t)(b * P + p) * N + n];
            float pb = isfinite(mv) ? bt[delta] : 0.f;
            float logit = LOGIT_CLIP * tanhf(acc[i][j] * INV_SQRT_E) + pb + mv;
            out[(size_t)(b * P + p) * N + n] = logit;
        }
    }
}

// ---------------------------------------------------------------------------
// Top-k (k=20) + temperature + renormalize, in place on d_out.
// One wave per row. Radix-select (32 ballot steps) finds the exact 20th
// largest value T; selection = {x > T} + {x == T, lowest index} (same
// tie-break as jax.lax.top_k). Softmax over selected relative to T.
// ---------------------------------------------------------------------------
__global__ __launch_bounds__(256) void topk_kernel(float* __restrict__ io)
{
    const int wv = threadIdx.x >> 6, lane = threadIdx.x & 63;
    const long row = (long)blockIdx.x * 4 + wv;
    float* r = io + row * N;

    float x[4];
    unsigned u[4];
    #pragma unroll
    for (int j = 0; j < 4; ++j) {
        int n = lane + 64 * j;
        bool valid = n < N;
        x[j] = valid ? r[n] : -INFINITY;
        unsigned bb = __float_as_uint(x[j]);
        // orderable mapping: larger float <-> larger uint; invalid -> 0 (min)
        u[j] = valid ? ((bb & 0x80000000u) ? ~bb : (bb | 0x80000000u)) : 0u;
    }

    // radix-select: after the loop, p == orderable(20th largest value)
    unsigned p = 0;
    for (int i = 31; i >= 0; --i) {
        unsigned c = p | (1u << i);
        int cnt = 0;
        #pragma unroll
        for (int j = 0; j < 4; ++j)
            cnt += (int)__popcll(__ballot(u[j] >= c));
        if (cnt >= TOP_K) p = c;
    }

    // elements strictly above threshold
    int cnt_gt = 0;
    #pragma unroll
    for (int j = 0; j < 4; ++j)
        cnt_gt += (int)__popcll(__ballot(u[j] > p));
    const int needed = TOP_K - cnt_gt;

    // select ties (u == p) in index order (n = lane + 64*j -> j-major)
    const unsigned long long lt_mask = (1ull << lane) - 1ull;
    bool sel[4];
    int eq_before = 0;
    #pragma unroll
    for (int j = 0; j < 4; ++j) {
        unsigned long long em = __ballot(u[j] == p);
        int myrank = eq_before + (int)__popcll(em & lt_mask);
        sel[j] = (u[j] > p) || ((u[j] == p) && (myrank < needed));
        eq_before += (int)__popcll(em);
    }

    // invert orderable mapping to get threshold as float
    unsigned tb = (p & 0x80000000u) ? (p & 0x7FFFFFFFu) : ~p;
    float Tf = __uint_as_float(tb);

    float e[4];
    float sum = 0.f;
    if (isfinite(Tf)) {
        #pragma unroll
        for (int j = 0; j < 4; ++j) {
            e[j] = sel[j] ? __expf((x[j] - Tf) * INV_TEMP) : 0.f;
            sum += e[j];
        }
    } else {
        // fully-masked row: selected entries are equal -> uniform weights
        #pragma unroll
        for (int j = 0; j < 4; ++j) {
            e[j] = sel[j] ? 1.f : 0.f;
            sum += e[j];
        }
    }
    #pragma unroll
    for (int off = 32; off > 0; off >>= 1) sum += __shfl_xor(sum, off);
    float inv = 1.f / sum;
    #pragma unroll
    for (int j = 0; j < 4; ++j) {
        int n = lane + 64 * j;
        if (n < N) r[n] = e[j] * inv;
    }
}

// ---------------------------------------------------------------------------
extern "C" void kernel_launch(void* const* d_in, const int* in_sizes, int n_in,
                              void* d_out, int out_size, void* d_ws, size_t ws_size,
                              hipStream_t stream) {
    const float* nodes = (const float*)d_in[0];
    const float* first = (const float*)d_in[1];
    const float* last  = (const float*)d_in[2];
    const float* mask  = (const float*)d_in[3];
    const int*   gid   = (const int*)d_in[4];
    const int*   cmp   = (const int*)d_in[5];
    const float* Wqf   = (const float*)d_in[6];
    const float* Wql   = (const float*)d_in[7];
    const float* Wk    = (const float*)d_in[8];
    const float* Wv    = (const float*)d_in[9];
    const float* Wc    = (const float*)d_in[10];
    const float* bc    = (const float*)d_in[11];
    const float* btab  = (const float*)d_in[12];
    float* out = (float*)d_out;

    float* ws   = (float*)d_ws;
    const size_t SLOT = (size_t)B * P * E;   // 6,553,600 floats
    float* qb  = ws;                 // q, later reused for mh
    float* kb  = ws + SLOT;
    float* vb  = ws + 2 * SLOT;
    float* ao  = ws + 3 * SLOT;      // attention output (concat heads)

    const int M = B * P;             // 51200 rows (= B*N too)

    // q = first@Wqf + last@Wql ; {k,v} = nodes@{Wk,Wv} fused
    proj_kernel<<<M / 64, 256, 0, stream>>>(first, Wqf, last, Wql, nullptr, qb);
    kv_proj_kernel<<<M / 64, 256, 0, stream>>>(nodes, Wk, Wv, kb, vb);

    // masked MHA (bound-softmax single pass, XCD-aware remap)
    attn_kernel<<<B * H, 256, 0, stream>>>(qb, kb, vb, mask, ao);

    // mh = ao @ Wc + bc   (into q's slot — q is dead now)
    proj_kernel<<<M / 64, 256, 0, stream>>>(ao, Wc, nullptr, nullptr, bc, qb);

    // pointer logits into d_out (double-LDS GEMM)
    dim3 pgrid((N + 63) / 64, (P + 63) / 64, B);
    pointer_kernel<<<pgrid, 256, 0, stream>>>(qb, nodes, mask, gid, cmp, btab, out);

    // top-k + renormalize in place
    topk_kernel<<<(B * P) / 4, 256, 0, stream>>>(out);
}

// Round 8
// 580.216 us; speedup vs baseline: 1.6463x; 1.0520x over previous
//
#include <hip/hip_runtime.h>
#include <hip/hip_bf16.h>
#include <math.h>

// Problem constants (fixed by setup_inputs)
constexpr int B = 256, P = 200, N = 200, E = 128, H = 8, D = 16;
constexpr float INV_SQRT_D = 0.25f;              // 1/sqrt(16)
constexpr float INV_SQRT_E = 0.08838834764831845f; // 1/sqrt(128)
constexpr float LOGIT_CLIP = 10.0f;
constexpr float INV_TEMP = 1.25f;                // 1/0.8
constexpr int TOP_K = 20;
constexpr int MAX_DELTA = 4;

__device__ __forceinline__ float dot4(float4 a, float4 b) {
    return a.x*b.x + a.y*b.y + a.z*b.z + a.w*b.w;
}

// ---------------------------------------------------------------------------
// GEMM: out[M,128] = X1[M,128] @ W1[128,128] (+ X2 @ W2) (+ bias)
// v2: 32 rows/block (grid 1600 -> ~6 waves/SIMD), W staged in LDS in
// K-chunks of 16 with register-prefetch double buffering — no global
// loads in the FMA loop (the R1-R7 version streamed W from global inside
// the inner loop at L2 latency with only 3 waves/SIMD to hide it).
// Thread tile: 4 rows (rg + 8*i) x 4 cols (eg*4..+3).
// ---------------------------------------------------------------------------
__global__ __launch_bounds__(256) void proj_kernel(
    const float* __restrict__ X1, const float* __restrict__ W1,
    const float* __restrict__ X2, const float* __restrict__ W2,
    const float* __restrict__ bias, float* __restrict__ out)
{
    __shared__ float4 xs[32][32];       // 32 rows x 128 floats (16 KB)
    __shared__ float4 ws[2][16][32];    // 16 k-rows x 128 floats, dbuf (16 KB)
    const int tid = threadIdx.x;
    const int eg = tid & 31;            // col group: cols eg*4..eg*4+3
    const int rg = tid >> 5;            // 0..7; rows rg + 8*i
    const long base = (long)blockIdx.x * 32;

    float acc[4][4];
    #pragma unroll
    for (int i = 0; i < 4; ++i)
        #pragma unroll
        for (int j = 0; j < 4; ++j) acc[i][j] = 0.f;

    for (int pass = 0; pass < 2; ++pass) {
        const float* X = pass ? X2 : X1;
        const float* W = pass ? W2 : W1;
        if (!X) break;
        if (pass) __syncthreads();      // xs/ws about to be overwritten
        const float4* X4 = (const float4*)X;
        const float4* W4 = (const float4*)W;
        // stage X tile (1024 float4) + W chunk 0 (512 float4)
        #pragma unroll
        for (int t = 0; t < 4; ++t) {
            int idx = tid + 256 * t;
            int r = idx >> 5, c = idx & 31;
            xs[r][c] = X4[(base + r) * 32 + c];
        }
        #pragma unroll
        for (int t = 0; t < 2; ++t) {
            int idx = tid + 256 * t;
            int r = idx >> 5, c = idx & 31;
            ws[0][r][c] = W4[r * 32 + c];
        }
        __syncthreads();

        for (int kc = 0; kc < 8; ++kc) {
            const int cur = kc & 1;
            // prefetch next W chunk into registers (latency hides under FMA)
            float4 pf0, pf1;
            if (kc < 7) {
                int i0 = tid, i1 = tid + 256;
                pf0 = W4[((kc + 1) * 16 + (i0 >> 5)) * 32 + (i0 & 31)];
                pf1 = W4[((kc + 1) * 16 + (i1 >> 5)) * 32 + (i1 & 31)];
            }
            // compute on ws[cur]: k = kc*16 .. kc*16+15
            #pragma unroll
            for (int k4 = 0; k4 < 4; ++k4) {
                float4 xv[4];
                #pragma unroll
                for (int i = 0; i < 4; ++i)
                    xv[i] = xs[rg + 8 * i][kc * 4 + k4];   // 2-addr broadcast
                float4 w0 = ws[cur][k4 * 4 + 0][eg];
                float4 w1 = ws[cur][k4 * 4 + 1][eg];
                float4 w2 = ws[cur][k4 * 4 + 2][eg];
                float4 w3 = ws[cur][k4 * 4 + 3][eg];
                #pragma unroll
                for (int i = 0; i < 4; ++i) {
                    acc[i][0] += xv[i].x*w0.x + xv[i].y*w1.x + xv[i].z*w2.x + xv[i].w*w3.x;
                    acc[i][1] += xv[i].x*w0.y + xv[i].y*w1.y + xv[i].z*w2.y + xv[i].w*w3.y;
                    acc[i][2] += xv[i].x*w0.z + xv[i].y*w1.z + xv[i].z*w2.z + xv[i].w*w3.z;
                    acc[i][3] += xv[i].x*w0.w + xv[i].y*w1.w + xv[i].z*w2.w + xv[i].w*w3.w;
                }
            }
            if (kc < 7) {
                // write prefetched chunk into the other buffer.
                // safe: ws[cur^1] was last READ in iter kc-1, which ended
                // with this same barrier; current readers use ws[cur].
                int i0 = tid, i1 = tid + 256;
                ws[cur ^ 1][i0 >> 5][i0 & 31] = pf0;
                ws[cur ^ 1][i1 >> 5][i1 & 31] = pf1;
                __syncthreads();
            }
        }
    }

    float4 bv = make_float4(0.f, 0.f, 0.f, 0.f);
    if (bias) bv = *(const float4*)&bias[eg * 4];
    float4* out4 = (float4*)out;
    #pragma unroll
    for (int i = 0; i < 4; ++i) {
        out4[(base + rg + 8 * i) * 32 + eg] =
            make_float4(acc[i][0]+bv.x, acc[i][1]+bv.y, acc[i][2]+bv.z, acc[i][3]+bv.w);
    }
}

// ---------------------------------------------------------------------------
// Fused K+V projection, same v2 structure (two W streams, two acc sets).
// ---------------------------------------------------------------------------
__global__ __launch_bounds__(256) void kv_proj_kernel(
    const float* __restrict__ X, const float* __restrict__ Wk,
    const float* __restrict__ Wv, float* __restrict__ outK,
    float* __restrict__ outV)
{
    __shared__ float4 xs[32][32];
    __shared__ float4 wsk[2][16][32];
    __shared__ float4 wsv[2][16][32];
    const int tid = threadIdx.x;
    const int eg = tid & 31;
    const int rg = tid >> 5;
    const long base = (long)blockIdx.x * 32;

    float acck[4][4], accv[4][4];
    #pragma unroll
    for (int i = 0; i < 4; ++i)
        #pragma unroll
        for (int j = 0; j < 4; ++j) { acck[i][j] = 0.f; accv[i][j] = 0.f; }

    const float4* X4 = (const float4*)X;
    const float4* Wk4 = (const float4*)Wk;
    const float4* Wv4 = (const float4*)Wv;
    #pragma unroll
    for (int t = 0; t < 4; ++t) {
        int idx = tid + 256 * t;
        int r = idx >> 5, c = idx & 31;
        xs[r][c] = X4[(base + r) * 32 + c];
    }
    #pragma unroll
    for (int t = 0; t < 2; ++t) {
        int idx = tid + 256 * t;
        int r = idx >> 5, c = idx & 31;
        wsk[0][r][c] = Wk4[r * 32 + c];
        wsv[0][r][c] = Wv4[r * 32 + c];
    }
    __syncthreads();

    for (int kc = 0; kc < 8; ++kc) {
        const int cur = kc & 1;
        float4 pk0, pk1, pv0, pv1;
        if (kc < 7) {
            int i0 = tid, i1 = tid + 256;
            int a0 = ((kc + 1) * 16 + (i0 >> 5)) * 32 + (i0 & 31);
            int a1 = ((kc + 1) * 16 + (i1 >> 5)) * 32 + (i1 & 31);
            pk0 = Wk4[a0]; pk1 = Wk4[a1];
            pv0 = Wv4[a0]; pv1 = Wv4[a1];
        }
        #pragma unroll
        for (int k4 = 0; k4 < 4; ++k4) {
            float4 xv[4];
            #pragma unroll
            for (int i = 0; i < 4; ++i)
                xv[i] = xs[rg + 8 * i][kc * 4 + k4];
            float4 k0 = wsk[cur][k4 * 4 + 0][eg];
            float4 k1 = wsk[cur][k4 * 4 + 1][eg];
            float4 k2 = wsk[cur][k4 * 4 + 2][eg];
            float4 k3 = wsk[cur][k4 * 4 + 3][eg];
            float4 v0 = wsv[cur][k4 * 4 + 0][eg];
            float4 v1 = wsv[cur][k4 * 4 + 1][eg];
            float4 v2 = wsv[cur][k4 * 4 + 2][eg];
            float4 v3 = wsv[cur][k4 * 4 + 3][eg];
            #pragma unroll
            for (int i = 0; i < 4; ++i) {
                acck[i][0] += xv[i].x*k0.x + xv[i].y*k1.x + xv[i].z*k2.x + xv[i].w*k3.x;
                acck[i][1] += xv[i].x*k0.y + xv[i].y*k1.y + xv[i].z*k2.y + xv[i].w*k3.y;
                acck[i][2] += xv[i].x*k0.z + xv[i].y*k1.z + xv[i].z*k2.z + xv[i].w*k3.z;
                acck[i][3] += xv[i].x*k0.w + xv[i].y*k1.w + xv[i].z*k2.w + xv[i].w*k3.w;
                accv[i][0] += xv[i].x*v0.x + xv[i].y*v1.x + xv[i].z*v2.x + xv[i].w*v3.x;
                accv[i][1] += xv[i].x*v0.y + xv[i].y*v1.y + xv[i].z*v2.y + xv[i].w*v3.y;
                accv[i][2] += xv[i].x*v0.z + xv[i].y*v1.z + xv[i].z*v2.z + xv[i].w*v3.z;
                accv[i][3] += xv[i].x*v0.w + xv[i].y*v1.w + xv[i].z*v2.w + xv[i].w*v3.w;
            }
        }
        if (kc < 7) {
            int i0 = tid, i1 = tid + 256;
            wsk[cur ^ 1][i0 >> 5][i0 & 31] = pk0;
            wsk[cur ^ 1][i1 >> 5][i1 & 31] = pk1;
            wsv[cur ^ 1][i0 >> 5][i0 & 31] = pv0;
            wsv[cur ^ 1][i1 >> 5][i1 & 31] = pv1;
            __syncthreads();
        }
    }

    float4* outK4 = (float4*)outK;
    float4* outV4 = (float4*)outV;
    #pragma unroll
    for (int i = 0; i < 4; ++i) {
        outK4[(base + rg + 8 * i) * 32 + eg] =
            make_float4(acck[i][0], acck[i][1], acck[i][2], acck[i][3]);
        outV4[(base + rg + 8 * i) * 32 + eg] =
            make_float4(accv[i][0], accv[i][1], accv[i][2], accv[i][3]);
    }
}

// ---------------------------------------------------------------------------
// Attention: bound-softmax single pass. One block (256 thr) per (b,h);
// thread p owns one q-row. No online rescaling: M = |q|*max|k| >= every
// score+mask (mask <= 0), so w = exp(s+mask-M) in (0,1], l = sum w,
// out = (sum w*v)/l — ratios identical to softmax (offset cancels).
// exp(-inf) = 0 handles masked entries branch-free.
// XCD-aware remap keeps same-b blocks on one XCD (mask/k/v L2 reuse).
// ---------------------------------------------------------------------------
__global__ __launch_bounds__(256) void attn_kernel(
    const float* __restrict__ q, const float* __restrict__ k,
    const float* __restrict__ v, const float* __restrict__ mask,
    float* __restrict__ out)
{
    __shared__ float4 ks[N][4];
    __shared__ float4 vs[N][4];
    __shared__ float red[4];
    const int raw = blockIdx.x;
    const int g = raw >> 6, rr6 = raw & 63;
    const int h = rr6 >> 3;
    const int b = g * 8 + (rr6 & 7);
    const int tid = threadIdx.x;

    const float4* k4 = (const float4*)k;
    const float4* v4 = (const float4*)v;
    for (int idx = tid; idx < N * 4; idx += 256) {
        int n = idx >> 2, c = idx & 3;
        size_t off = (size_t)(b * N + n) * 32 + h * 4 + c;
        ks[n][c] = k4[off];
        vs[n][c] = v4[off];
    }
    __syncthreads();

    // kmax2 = max_n |k_n|^2 (block-wide, one time)
    float nrm = 0.f;
    if (tid < N) {
        float4 a0 = ks[tid][0], a1 = ks[tid][1], a2 = ks[tid][2], a3 = ks[tid][3];
        nrm = dot4(a0,a0) + dot4(a1,a1) + dot4(a2,a2) + dot4(a3,a3);
    }
    float wm = nrm;
    #pragma unroll
    for (int off = 32; off > 0; off >>= 1) wm = fmaxf(wm, __shfl_xor(wm, off));
    if ((tid & 63) == 0) red[tid >> 6] = wm;
    __syncthreads();
    const float kmax2 = fmaxf(fmaxf(red[0], red[1]), fmaxf(red[2], red[3]));

    const int p = tid;
    if (p >= P) return;

    // q prescaled by 1/sqrt(D)
    const float4* qr = (const float4*)q + (size_t)(b * P + p) * 32 + h * 4;
    float4 q0 = qr[0], q1 = qr[1], q2 = qr[2], q3 = qr[3];
    q0.x*=INV_SQRT_D; q0.y*=INV_SQRT_D; q0.z*=INV_SQRT_D; q0.w*=INV_SQRT_D;
    q1.x*=INV_SQRT_D; q1.y*=INV_SQRT_D; q1.z*=INV_SQRT_D; q1.w*=INV_SQRT_D;
    q2.x*=INV_SQRT_D; q2.y*=INV_SQRT_D; q2.z*=INV_SQRT_D; q2.w*=INV_SQRT_D;
    q3.x*=INV_SQRT_D; q3.y*=INV_SQRT_D; q3.z*=INV_SQRT_D; q3.w*=INV_SQRT_D;
    const float qn2 = dot4(q0,q0) + dot4(q1,q1) + dot4(q2,q2) + dot4(q3,q3);
    const float M = sqrtf(qn2 * kmax2);   // >= any |q.k| (Cauchy-Schwarz)

    const float4* m4 = (const float4*)(mask + (size_t)(b * P + p) * N);

    float l = 0.f;
    float o[16];
    #pragma unroll
    for (int d = 0; d < 16; ++d) o[d] = 0.f;

    #pragma unroll 2
    for (int n4 = 0; n4 < N / 4; ++n4) {
        float4 mv = m4[n4];
        float mvf[4] = {mv.x, mv.y, mv.z, mv.w};
        #pragma unroll
        for (int j = 0; j < 4; ++j) {
            int n = n4 * 4 + j;
            float s = dot4(q0, ks[n][0]) + dot4(q1, ks[n][1]) +
                      dot4(q2, ks[n][2]) + dot4(q3, ks[n][3]);
            float w = __expf(s + mvf[j] - M);
            l += w;
            float4 v0 = vs[n][0], v1 = vs[n][1], v2 = vs[n][2], v3 = vs[n][3];
            o[0]  += w*v0.x; o[1]  += w*v0.y; o[2]  += w*v0.z; o[3]  += w*v0.w;
            o[4]  += w*v1.x; o[5]  += w*v1.y; o[6]  += w*v1.z; o[7]  += w*v1.w;
            o[8]  += w*v2.x; o[9]  += w*v2.y; o[10] += w*v2.z; o[11] += w*v2.w;
            o[12] += w*v3.x; o[13] += w*v3.y; o[14] += w*v3.z; o[15] += w*v3.w;
        }
    }

    float inv_l = 1.f / l;
    float4* out4 = (float4*)out;
    size_t ob = (size_t)(b * P + p) * 32 + h * 4;
    #pragma unroll
    for (int c = 0; c < 4; ++c)
        out4[ob + c] = make_float4(o[c*4]*inv_l, o[c*4+1]*inv_l,
                                   o[c*4+2]*inv_l, o[c*4+3]*inv_l);
}

// ---------------------------------------------------------------------------
// Pointer scores + logits: sc = mh[b] @ nodes[b]^T, fused tanh/bias/mask.
// Double-LDS GEMM: 64x64 tile, K in 2 steps of 64, both operand tiles
// staged in LDS. Thread tile 4x4 interleaved (stride 16).
// ---------------------------------------------------------------------------
__global__ __launch_bounds__(256) void pointer_kernel(
    const float* __restrict__ mh, const float* __restrict__ nodes,
    const float* __restrict__ mask, const int* __restrict__ gid,
    const int* __restrict__ cmp, const float* __restrict__ btab,
    float* __restrict__ out)
{
    __shared__ float4 as[64][17];     // mh tile:    64 p-rows x 64 k (pad 17)
    __shared__ float4 bs[64][17];     // nodes tile: 64 n-rows x 64 k (pad 17)
    const int b = blockIdx.z;
    const int p_base = blockIdx.y * 64;
    const int n_base = blockIdx.x * 64;
    const int tid = threadIdx.x;
    const int pi = tid >> 4;          // 0..15
    const int ni = tid & 15;          // 0..15

    const float4* mh4 = (const float4*)mh;
    const float4* nodes4 = (const float4*)nodes;

    float acc[4][4];
    #pragma unroll
    for (int i = 0; i < 4; ++i)
        #pragma unroll
        for (int j = 0; j < 4; ++j) acc[i][j] = 0.f;

    for (int ks = 0; ks < 2; ++ks) {
        if (ks) __syncthreads();
        #pragma unroll
        for (int t = 0; t < 4; ++t) {
            int idx = tid + 256 * t;
            int r = idx >> 4, c = idx & 15;
            int pr = p_base + r; pr = pr < P ? pr : P - 1;
            int nr = n_base + r; nr = nr < N ? nr : N - 1;
            as[r][c] = mh4[(size_t)(b * P + pr) * 32 + ks * 16 + c];
            bs[r][c] = nodes4[(size_t)(b * N + nr) * 32 + ks * 16 + c];
        }
        __syncthreads();

        for (int c4 = 0; c4 < 16; ++c4) {
            float4 a[4], w[4];
            #pragma unroll
            for (int i = 0; i < 4; ++i) a[i] = as[pi + 16 * i][c4];
            #pragma unroll
            for (int j = 0; j < 4; ++j) w[j] = bs[ni + 16 * j][c4];
            #pragma unroll
            for (int i = 0; i < 4; ++i)
                #pragma unroll
                for (int j = 0; j < 4; ++j)
                    acc[i][j] += dot4(a[i], w[j]);
        }
    }

    float bt[MAX_DELTA + 1];
    #pragma unroll
    for (int t = 0; t <= MAX_DELTA; ++t) bt[t] = btab[t];

    #pragma unroll
    for (int i = 0; i < 4; ++i) {
        int p = p_base + pi + 16 * i;
        if (p >= P) continue;
        int cm = cmp[b * P + p];
        #pragma unroll
        for (int j = 0; j < 4; ++j) {
            int n = n_base + ni + 16 * j;
            if (n >= N) continue;
            int g = gid[b * N + n];
            int delta = g - cm;
            delta = delta < 0 ? 0 : (delta > MAX_DELTA ? MAX_DELTA : delta);
            float mv = mask[(size_t)(b * P + p) * N + n];
            float pb = isfinite(mv) ? bt[delta] : 0.f;
            float logit = LOGIT_CLIP * tanhf(acc[i][j] * INV_SQRT_E) + pb + mv;
            out[(size_t)(b * P + p) * N + n] = logit;
        }
    }
}

// ---------------------------------------------------------------------------
// Top-k (k=20) + temperature + renormalize, in place on d_out.
// One wave per row. Radix-select (32 ballot steps) finds the exact 20th
// largest value T; selection = {x > T} + {x == T, lowest index} (same
// tie-break as jax.lax.top_k). Softmax over selected relative to T.
// ---------------------------------------------------------------------------
__global__ __launch_bounds__(256) void topk_kernel(float* __restrict__ io)
{
    const int wv = threadIdx.x >> 6, lane = threadIdx.x & 63;
    const long row = (long)blockIdx.x * 4 + wv;
    float* r = io + row * N;

    float x[4];
    unsigned u[4];
    #pragma unroll
    for (int j = 0; j < 4; ++j) {
        int n = lane + 64 * j;
        bool valid = n < N;
        x[j] = valid ? r[n] : -INFINITY;
        unsigned bb = __float_as_uint(x[j]);
        // orderable mapping: larger float <-> larger uint; invalid -> 0 (min)
        u[j] = valid ? ((bb & 0x80000000u) ? ~bb : (bb | 0x80000000u)) : 0u;
    }

    // radix-select: after the loop, p == orderable(20th largest value)
    unsigned p = 0;
    for (int i = 31; i >= 0; --i) {
        unsigned c = p | (1u << i);
        int cnt = 0;
        #pragma unroll
        for (int j = 0; j < 4; ++j)
            cnt += (int)__popcll(__ballot(u[j] >= c));
        if (cnt >= TOP_K) p = c;
    }

    // elements strictly above threshold
    int cnt_gt = 0;
    #pragma unroll
    for (int j = 0; j < 4; ++j)
        cnt_gt += (int)__popcll(__ballot(u[j] > p));
    const int needed = TOP_K - cnt_gt;

    // select ties (u == p) in index order (n = lane + 64*j -> j-major)
    const unsigned long long lt_mask = (1ull << lane) - 1ull;
    bool sel[4];
    int eq_before = 0;
    #pragma unroll
    for (int j = 0; j < 4; ++j) {
        unsigned long long em = __ballot(u[j] == p);
        int myrank = eq_before + (int)__popcll(em & lt_mask);
        sel[j] = (u[j] > p) || ((u[j] == p) && (myrank < needed));
        eq_before += (int)__popcll(em);
    }

    // invert orderable mapping to get threshold as float
    unsigned tb = (p & 0x80000000u) ? (p & 0x7FFFFFFFu) : ~p;
    float Tf = __uint_as_float(tb);

    float e[4];
    float sum = 0.f;
    if (isfinite(Tf)) {
        #pragma unroll
        for (int j = 0; j < 4; ++j) {
            e[j] = sel[j] ? __expf((x[j] - Tf) * INV_TEMP) : 0.f;
            sum += e[j];
        }
    } else {
        // fully-masked row: selected entries are equal -> uniform weights
        #pragma unroll
        for (int j = 0; j < 4; ++j) {
            e[j] = sel[j] ? 1.f : 0.f;
            sum += e[j];
        }
    }
    #pragma unroll
    for (int off = 32; off > 0; off >>= 1) sum += __shfl_xor(sum, off);
    float inv = 1.f / sum;
    #pragma unroll
    for (int j = 0; j < 4; ++j) {
        int n = lane + 64 * j;
        if (n < N) r[n] = e[j] * inv;
    }
}

// ---------------------------------------------------------------------------
extern "C" void kernel_launch(void* const* d_in, const int* in_sizes, int n_in,
                              void* d_out, int out_size, void* d_ws, size_t ws_size,
                              hipStream_t stream) {
    const float* nodes = (const float*)d_in[0];
    const float* first = (const float*)d_in[1];
    const float* last  = (const float*)d_in[2];
    const float* mask  = (const float*)d_in[3];
    const int*   gid   = (const int*)d_in[4];
    const int*   cmp   = (const int*)d_in[5];
    const float* Wqf   = (const float*)d_in[6];
    const float* Wql   = (const float*)d_in[7];
    const float* Wk    = (const float*)d_in[8];
    const float* Wv    = (const float*)d_in[9];
    const float* Wc    = (const float*)d_in[10];
    const float* bc    = (const float*)d_in[11];
    const float* btab  = (const float*)d_in[12];
    float* out = (float*)d_out;

    float* ws   = (float*)d_ws;
    const size_t SLOT = (size_t)B * P * E;   // 6,553,600 floats
    float* qb  = ws;                 // q, later reused for mh
    float* kb  = ws + SLOT;
    float* vb  = ws + 2 * SLOT;
    float* ao  = ws + 3 * SLOT;      // attention output (concat heads)

    const int M = B * P;             // 51200 rows (= B*N too)

    // q = first@Wqf + last@Wql ; {k,v} = nodes@{Wk,Wv} fused
    proj_kernel<<<M / 32, 256, 0, stream>>>(first, Wqf, last, Wql, nullptr, qb);
    kv_proj_kernel<<<M / 32, 256, 0, stream>>>(nodes, Wk, Wv, kb, vb);

    // masked MHA (bound-softmax single pass, XCD-aware remap)
    attn_kernel<<<B * H, 256, 0, stream>>>(qb, kb, vb, mask, ao);

    // mh = ao @ Wc + bc   (into q's slot — q is dead now)
    proj_kernel<<<M / 32, 256, 0, stream>>>(ao, Wc, nullptr, nullptr, bc, qb);

    // pointer logits into d_out (double-LDS GEMM)
    dim3 pgrid((N + 63) / 64, (P + 63) / 64, B);
    pointer_kernel<<<pgrid, 256, 0, stream>>>(qb, nodes, mask, gid, cmp, btab, out);

    // top-k + renormalize in place
    topk_kernel<<<(B * P) / 4, 256, 0, stream>>>(out);
}